// Round 6
// baseline (1413.683 us; speedup 1.0000x reference)
//
#include <hip/hip_runtime.h>

#define N_NODES 100000
#define N_EDGES 1600000
#define F_IN 128
#define HID 64
#define NLAYERS 4
#define N_GRAPHS 512
#define N_CLASSES 10
#define N_TILES ((N_NODES + 255) / 256)   // 391

typedef unsigned int uint_t;
typedef unsigned short ushort_t;

__device__ __forceinline__ float lo_bf(uint_t w) { return __uint_as_float(w << 16); }
__device__ __forceinline__ float hi_bf(uint_t w) { return __uint_as_float(w & 0xffff0000u); }
__device__ __forceinline__ ushort_t f2bf(float f) {
    uint_t u = __float_as_uint(f);
    u += 0x7fffu + ((u >> 16) & 1u);   // round-to-nearest-even
    return (ushort_t)(u >> 16);
}

// ---------------- CSR build ----------------
__global__ __launch_bounds__(256) void k_degree(const int* __restrict__ dst, int* __restrict__ deg) {
    int base = blockIdx.x * 1024 + threadIdx.x;
    #pragma unroll
    for (int j = 0; j < 4; ++j) {
        int e = base + j * 256;
        if (e < N_EDGES) {
            int d = dst[e];
            if ((uint_t)d < (uint_t)N_NODES) atomicAdd(&deg[d], 1);
        }
    }
}

__global__ __launch_bounds__(256) void k_tilesum(const int* __restrict__ deg, int* __restrict__ bsum) {
    __shared__ int sh[256];
    int tid = threadIdx.x;
    int i = blockIdx.x * 256 + tid;
    sh[tid] = (i < N_NODES) ? deg[i] : 0;
    __syncthreads();
    for (int off = 128; off > 0; off >>= 1) {
        if (tid < off) sh[tid] += sh[tid + off];
        __syncthreads();
    }
    if (tid == 0) bsum[blockIdx.x] = sh[0];
}

__global__ __launch_bounds__(512) void k_tilescan(const int* __restrict__ bsum, int* __restrict__ boff) {
    __shared__ int sh[512];
    int tid = threadIdx.x;
    sh[tid] = (tid < N_TILES) ? bsum[tid] : 0;
    __syncthreads();
    for (int off = 1; off < 512; off <<= 1) {
        int t = (tid >= off) ? sh[tid - off] : 0;
        __syncthreads();
        sh[tid] += t;
        __syncthreads();
    }
    if (tid < N_TILES) boff[tid + 1] = sh[tid];
    if (tid == 0) boff[0] = 0;
}

__global__ __launch_bounds__(256) void k_tileapply(const int* __restrict__ deg, const int* __restrict__ boff,
                                                   int* __restrict__ row_ptr) {
    __shared__ int sh[256];
    int tid = threadIdx.x, b = blockIdx.x;
    int i = b * 256 + tid;
    sh[tid] = (i < N_NODES) ? deg[i] : 0;
    __syncthreads();
    for (int off = 1; off < 256; off <<= 1) {
        int t = (tid >= off) ? sh[tid - off] : 0;
        __syncthreads();
        sh[tid] += t;
        __syncthreads();
    }
    if (i < N_NODES) row_ptr[i + 1] = boff[b] + sh[tid];
    if (i == 0) row_ptr[0] = 0;
}

__global__ __launch_bounds__(256) void k_fill(const int* __restrict__ src, const int* __restrict__ dst,
                                              int* __restrict__ cursor, int* __restrict__ col_src) {
    int base = blockIdx.x * 1024 + threadIdx.x;
    int e0 = base, e1 = base + 256, e2 = base + 512, e3 = base + 768;
    bool v0 = e0 < N_EDGES, v1 = e1 < N_EDGES, v2 = e2 < N_EDGES, v3 = e3 < N_EDGES;
    int d0 = v0 ? dst[e0] : 0, d1 = v1 ? dst[e1] : 0, d2 = v2 ? dst[e2] : 0, d3 = v3 ? dst[e3] : 0;
    int s0 = v0 ? src[e0] : 0, s1 = v1 ? src[e1] : 0, s2 = v2 ? src[e2] : 0, s3 = v3 ? src[e3] : 0;
    v0 = v0 && (uint_t)d0 < (uint_t)N_NODES;
    v1 = v1 && (uint_t)d1 < (uint_t)N_NODES;
    v2 = v2 && (uint_t)d2 < (uint_t)N_NODES;
    v3 = v3 && (uint_t)d3 < (uint_t)N_NODES;
    int p0 = v0 ? atomicAdd(&cursor[d0], 1) : 0;
    int p1 = v1 ? atomicAdd(&cursor[d1], 1) : 0;
    int p2 = v2 ? atomicAdd(&cursor[d2], 1) : 0;
    int p3 = v3 ? atomicAdd(&cursor[d3], 1) : 0;
    if ((uint_t)s0 >= (uint_t)N_NODES) s0 = 0;
    if ((uint_t)s1 >= (uint_t)N_NODES) s1 = 0;
    if ((uint_t)s2 >= (uint_t)N_NODES) s2 = 0;
    if ((uint_t)s3 >= (uint_t)N_NODES) s3 = 0;
    if (v0 && (uint_t)p0 < (uint_t)N_EDGES) col_src[p0] = s0;
    if (v1 && (uint_t)p1 < (uint_t)N_EDGES) col_src[p1] = s1;
    if (v2 && (uint_t)p2 < (uint_t)N_EDGES) col_src[p2] = s2;
    if (v3 && (uint_t)p3 < (uint_t)N_EDGES) col_src[p3] = s3;
}

// ---------------- aggregation on bf16 y (dim 64) ----------------
// u[node] = (1+eps)*y[node] + sum_{in edges} y[src] + b1
// One wave per node. 32 lanes cover a 128B bf16 row (uint = 2 cols).
// 2 edges per wave-instruction (gid = lane>>5), 8 unrolled streams.
__global__ __launch_bounds__(256) void k_aggregate_u(const uint_t* __restrict__ ybf,
                                                     const int* __restrict__ row_ptr,
                                                     const int* __restrict__ col_src,
                                                     const float* __restrict__ eps, int layer,
                                                     const float* __restrict__ b1,
                                                     float* __restrict__ u) {
    int wid = threadIdx.x >> 6, lane = threadIdx.x & 63;
    int gid = lane >> 5, l5 = lane & 31;
    int node = blockIdx.x * 4 + wid;
    if (node >= N_NODES) return;
    float one_eps = 1.0f + eps[layer];
    int e0 = row_ptr[node], e1 = row_ptr[node + 1];
    if (e0 < 0) e0 = 0;
    if (e1 > N_EDGES) e1 = N_EDGES;
    if (e1 < e0) e1 = e0;

    float ax[8], ay[8];
    #pragma unroll
    for (int j = 0; j < 8; ++j) { ax[j] = 0.f; ay[j] = 0.f; }

    for (int eb = e0; eb < e1; eb += 16) {
        #pragma unroll
        for (int j = 0; j < 8; ++j) {
            int ee = eb + 2 * j + gid;
            if (ee < e1) {
                int s = col_src[ee];
                if ((uint_t)s >= (uint_t)N_NODES) s = 0;
                uint_t w = ybf[(size_t)s * 32 + l5];
                ax[j] += lo_bf(w);
                ay[j] += hi_bf(w);
            }
        }
    }
    float sx = ((ax[0] + ax[1]) + (ax[2] + ax[3])) + ((ax[4] + ax[5]) + (ax[6] + ax[7]));
    float sy = ((ay[0] + ay[1]) + (ay[2] + ay[3])) + ((ay[4] + ay[5]) + (ay[6] + ay[7]));
    sx += __shfl_xor(sx, 32, 64);
    sy += __shfl_xor(sy, 32, 64);
    if (gid == 0) {
        uint_t wself = ybf[(size_t)node * 32 + l5];
        float ox = sx + one_eps * lo_bf(wself) + b1[2 * l5 + 0];
        float oy = sy + one_eps * hi_bf(wself) + b1[2 * l5 + 1];
        ((float2*)u)[(size_t)node * 32 + l5] = make_float2(ox, oy);
    }
}

// ---------------- GEMM1: ybf[N x 64](bf16) = A[N x K](f32) @ W[K x 64]  (no bias) ----------------
template <int K>
__global__ __launch_bounds__(256) void k_gemm_f32(const float* __restrict__ A,
                                                  const float* __restrict__ W,
                                                  ushort_t* __restrict__ out) {
    __shared__ float Wl[K * 64];
    int tid = threadIdx.x;
    for (int i = tid; i < K * 64; i += 256) Wl[i] = W[i];
    __syncthreads();
    int col = tid & 63, wv = tid >> 6;
    int base = blockIdx.x * 16 + wv * 4;
    const float* A0 = A + (size_t)base * K;
    const float* A1 = A0 + K;
    const float* A2 = A1 + K;
    const float* A3 = A2 + K;
    float acc0 = 0.f, acc1 = 0.f, acc2 = 0.f, acc3 = 0.f;
    #pragma unroll 8
    for (int k = 0; k < K; ++k) {
        float wk = Wl[k * 64 + col];
        acc0 += A0[k] * wk;
        acc1 += A1[k] * wk;
        acc2 += A2[k] * wk;
        acc3 += A3[k] * wk;
    }
    out[(size_t)(base + 0) * 64 + col] = f2bf(acc0);
    out[(size_t)(base + 1) * 64 + col] = f2bf(acc1);
    out[(size_t)(base + 2) * 64 + col] = f2bf(acc2);
    out[(size_t)(base + 3) * 64 + col] = f2bf(acc3);
}

// ---------------- GEMM2 with BN+ReLU fused on the A-load; pooling fused in epilogue ----------------
__global__ __launch_bounds__(256) void k_gemm_bn(const float* __restrict__ U,
                                                 const float* __restrict__ W,
                                                 const float* __restrict__ scsh,
                                                 const float* __restrict__ b2,
                                                 const int* __restrict__ batch, int layer,
                                                 float* __restrict__ pooled,
                                                 float* __restrict__ out) {
    __shared__ float Wl[64 * 64];
    __shared__ float Sc[64], Sh[64];
    int tid = threadIdx.x;
    for (int i = tid; i < 64 * 64; i += 256) Wl[i] = W[i];
    if (tid < 64) { Sc[tid] = scsh[tid]; Sh[tid] = scsh[64 + tid]; }
    __syncthreads();
    int col = tid & 63, wv = tid >> 6;
    float b = b2[col];
    int base = blockIdx.x * 16 + wv * 4;
    const float* A0 = U + (size_t)base * 64;
    const float* A1 = A0 + 64;
    const float* A2 = A1 + 64;
    const float* A3 = A2 + 64;
    float acc0 = b, acc1 = b, acc2 = b, acc3 = b;
    #pragma unroll 8
    for (int k = 0; k < 64; ++k) {
        float wk = Wl[k * 64 + col];
        float sck = Sc[k], shk = Sh[k];
        float v0 = fmaxf(fmaf(A0[k], sck, shk), 0.f);
        float v1 = fmaxf(fmaf(A1[k], sck, shk), 0.f);
        float v2 = fmaxf(fmaf(A2[k], sck, shk), 0.f);
        float v3 = fmaxf(fmaf(A3[k], sck, shk), 0.f);
        acc0 = fmaf(v0, wk, acc0);
        acc1 = fmaf(v1, wk, acc1);
        acc2 = fmaf(v2, wk, acc2);
        acc3 = fmaf(v3, wk, acc3);
    }
    acc0 = fmaxf(acc0, 0.f); acc1 = fmaxf(acc1, 0.f);
    acc2 = fmaxf(acc2, 0.f); acc3 = fmaxf(acc3, 0.f);
    out[(size_t)(base + 0) * 64 + col] = acc0;
    out[(size_t)(base + 1) * 64 + col] = acc1;
    out[(size_t)(base + 2) * 64 + col] = acc2;
    out[(size_t)(base + 3) * 64 + col] = acc3;
    // fused pooling: fire-and-forget coalesced atomics
    int g0 = batch[base + 0], g1 = batch[base + 1], g2 = batch[base + 2], g3 = batch[base + 3];
    if ((uint_t)g0 < (uint_t)N_GRAPHS) atomicAdd(&pooled[g0 * 256 + layer * 64 + col], acc0);
    if ((uint_t)g1 < (uint_t)N_GRAPHS) atomicAdd(&pooled[g1 * 256 + layer * 64 + col], acc1);
    if ((uint_t)g2 < (uint_t)N_GRAPHS) atomicAdd(&pooled[g2 * 256 + layer * 64 + col], acc2);
    if ((uint_t)g3 < (uint_t)N_GRAPHS) atomicAdd(&pooled[g3 * 256 + layer * 64 + col], acc3);
}

// ---------------- column stats over u [N_NODES x 64] ----------------
__global__ __launch_bounds__(256) void k_stats(const float* __restrict__ u, float* __restrict__ sums) {
    __shared__ float s1[256], s2[256];
    int tid = threadIdx.x;
    float a = 0.f, b = 0.f;
    for (size_t i = (size_t)blockIdx.x * 256 + tid; i < (size_t)N_NODES * 64; i += (size_t)gridDim.x * 256) {
        float v = u[i];
        a += v;
        b += v * v;
    }
    s1[tid] = a; s2[tid] = b;
    __syncthreads();
    if (tid < 128) { s1[tid] += s1[tid + 128]; s2[tid] += s2[tid + 128]; }
    __syncthreads();
    if (tid < 64) {
        atomicAdd(&sums[tid], s1[tid] + s1[tid + 64]);
        atomicAdd(&sums[64 + tid], s2[tid] + s2[tid + 64]);
    }
}

__global__ __launch_bounds__(64) void k_finalize(const float* __restrict__ sums,
                                                 const float* __restrict__ g,
                                                 const float* __restrict__ be,
                                                 float* __restrict__ scsh, float inv_n) {
    int c = threadIdx.x;
    float mean = sums[c] * inv_n;
    float var = sums[64 + c] * inv_n - mean * mean;
    if (var < 0.f) var = 0.f;
    float inv = rsqrtf(var + 1e-5f);
    float sc = inv * g[c];
    scsh[c] = sc;
    scsh[64 + c] = be[c] - mean * sc;
}

// ---------------- head ----------------
__global__ __launch_bounds__(64) void k_head1(const float* __restrict__ pooled,
                                              const float* __restrict__ W, const float* __restrict__ b,
                                              float* __restrict__ t1) {
    int g = blockIdx.x, lane = threadIdx.x;
    const float* p = pooled + g * 256;
    float acc = b[lane];
    for (int k = 0; k < 256; ++k) acc += p[k] * W[k * 64 + lane];
    t1[g * 64 + lane] = acc;
}

__global__ __launch_bounds__(64) void k_head2(const float* __restrict__ t1,
                                              const float* __restrict__ g_, const float* __restrict__ b_,
                                              float* __restrict__ scsh) {
    int c = threadIdx.x;
    float s = 0.f, q = 0.f;
    for (int r = 0; r < N_GRAPHS; ++r) {
        float v = t1[r * 64 + c];
        s += v; q += v * v;
    }
    float mean = s * (1.0f / N_GRAPHS);
    float var = q * (1.0f / N_GRAPHS) - mean * mean;
    if (var < 0.f) var = 0.f;
    float inv = rsqrtf(var + 1e-5f);
    float sc = inv * g_[c];
    scsh[c] = sc;
    scsh[64 + c] = b_[c] - mean * sc;
}

__global__ __launch_bounds__(64) void k_head3(const float* __restrict__ t1, const float* __restrict__ scsh,
                                              const float* __restrict__ W2, const float* __restrict__ b2,
                                              float* __restrict__ out) {
    __shared__ float v[64];
    __shared__ float o[16];
    int g = blockIdx.x, lane = threadIdx.x;
    float x = t1[g * 64 + lane] * scsh[lane] + scsh[64 + lane];
    v[lane] = fmaxf(x, 0.f);
    __syncthreads();
    if (lane < N_CLASSES) {
        float acc = b2[lane];
        for (int k = 0; k < 64; ++k) acc += v[k] * W2[k * N_CLASSES + lane];
        o[lane] = acc;
    }
    __syncthreads();
    if (lane < N_CLASSES) {
        float m = -1e30f;
        for (int k = 0; k < N_CLASSES; ++k) m = fmaxf(m, o[k]);
        float ssum = 0.f;
        for (int k = 0; k < N_CLASSES; ++k) ssum += expf(o[k] - m);
        out[g * N_CLASSES + lane] = o[lane] - m - logf(ssum);
    }
}

// ---------------- launch ----------------
extern "C" void kernel_launch(void* const* d_in, const int* in_sizes, int n_in,
                              void* d_out, int out_size, void* d_ws, size_t ws_size,
                              hipStream_t stream) {
    const float* x      = (const float*)d_in[0];
    const int*   ei     = (const int*)d_in[1];
    const int*   srcArr = ei;
    const int*   dstArr = ei + N_EDGES;
    const int*   batch  = (const int*)d_in[2];
    const float* eps    = (const float*)d_in[3];
    const float* W1_0   = (const float*)d_in[4];
    const float* b1_0   = (const float*)d_in[5];
    const float* g_0    = (const float*)d_in[6];
    const float* be_0   = (const float*)d_in[7];
    const float* W2_0   = (const float*)d_in[8];
    const float* b2_0   = (const float*)d_in[9];
    const float* W1_r   = (const float*)d_in[10];
    const float* b1_r   = (const float*)d_in[11];
    const float* g_r    = (const float*)d_in[12];
    const float* be_r   = (const float*)d_in[13];
    const float* W2_r   = (const float*)d_in[14];
    const float* b2_r   = (const float*)d_in[15];
    const float* lin1W  = (const float*)d_in[16];
    const float* lin1b  = (const float*)d_in[17];
    const float* bn_g   = (const float*)d_in[18];
    const float* bn_b   = (const float*)d_in[19];
    const float* lin2W  = (const float*)d_in[20];
    const float* lin2b  = (const float*)d_in[21];

    char* ws = (char*)d_ws;
    auto alloc = [&](size_t bytes) {
        char* p = ws;
        ws += (bytes + 255) & ~(size_t)255;
        return p;
    };
    int*      deg     = (int*)alloc((size_t)N_NODES * 4);
    int*      row_ptr = (int*)alloc(((size_t)N_NODES + 1) * 4);
    int*      cursor  = (int*)alloc(((size_t)N_NODES + 1) * 4);
    int*      bsum    = (int*)alloc((size_t)N_TILES * 4);
    int*      boff    = (int*)alloc(((size_t)N_TILES + 1) * 4);
    int*      col_src = (int*)alloc((size_t)N_EDGES * 4);
    ushort_t* ybf     = (ushort_t*)alloc((size_t)N_NODES * 64 * 2);
    float*    u       = (float*)alloc((size_t)N_NODES * 64 * 4);
    float*    hA      = (float*)alloc((size_t)N_NODES * 64 * 4);
    float*    hB      = (float*)alloc((size_t)N_NODES * 64 * 4);
    float*    statsA  = (float*)alloc(NLAYERS * 128 * 4);
    float*    scsh    = (float*)alloc(NLAYERS * 128 * 4);
    float*    pooled  = (float*)alloc((size_t)N_GRAPHS * 256 * 4);
    float*    t1      = (float*)alloc((size_t)N_GRAPHS * 64 * 4);
    float*    hscsh   = (float*)alloc(128 * 4);

    hipMemsetAsync(deg, 0, (size_t)N_NODES * 4, stream);
    hipMemsetAsync(statsA, 0, NLAYERS * 128 * 4, stream);
    hipMemsetAsync(pooled, 0, (size_t)N_GRAPHS * 256 * 4, stream);

    const int e4_grid = (N_EDGES + 1023) / 1024;
    k_degree<<<e4_grid, 256, 0, stream>>>(dstArr, deg);
    k_tilesum<<<N_TILES, 256, 0, stream>>>(deg, bsum);
    k_tilescan<<<1, 512, 0, stream>>>(bsum, boff);
    k_tileapply<<<N_TILES, 256, 0, stream>>>(deg, boff, row_ptr);
    hipMemcpyAsync(cursor, row_ptr, (size_t)N_NODES * 4, hipMemcpyDeviceToDevice, stream);
    k_fill<<<e4_grid, 256, 0, stream>>>(srcArr, dstArr, cursor, col_src);

    const int agg_grid  = N_NODES / 4;            // 25000, exact
    const int gemm_grid = N_NODES / 16;           // 6250, exact

    const float* hin = x;
    float* hping[2] = {hA, hB};
    for (int l = 0; l < NLAYERS; ++l) {
        const float *W1, *b1, *gg, *be, *W2, *b2;
        if (l == 0) { W1 = W1_0; b1 = b1_0; gg = g_0; be = be_0; W2 = W2_0; b2 = b2_0; }
        else {
            W1 = W1_r + (size_t)(l - 1) * 64 * 64;
            b1 = b1_r + (size_t)(l - 1) * 64;
            gg = g_r  + (size_t)(l - 1) * 64;
            be = be_r + (size_t)(l - 1) * 64;
            W2 = W2_r + (size_t)(l - 1) * 64 * 64;
            b2 = b2_r + (size_t)(l - 1) * 64;
        }
        float* hout = hping[l & 1];
        // y = bf16(h @ W1)   (bias folded into aggregate)
        if (l == 0) k_gemm_f32<128><<<gemm_grid, 256, 0, stream>>>(hin, W1, ybf);
        else        k_gemm_f32<64><<<gemm_grid, 256, 0, stream>>>(hin, W1, ybf);
        // u = (1+eps)*y + sum y[src] + b1
        k_aggregate_u<<<agg_grid, 256, 0, stream>>>((const uint_t*)ybf, row_ptr, col_src, eps, l, b1, u);
        k_stats<<<256, 256, 0, stream>>>(u, statsA + l * 128);
        k_finalize<<<1, 64, 0, stream>>>(statsA + l * 128, gg, be, scsh + l * 128, 1.0f / N_NODES);
        // h = relu( relu(bn(u)) @ W2 + b2 ); pooled += per-graph sums
        k_gemm_bn<<<gemm_grid, 256, 0, stream>>>(u, W2, scsh + l * 128, b2, batch, l, pooled, hout);
        hin = hout;
    }

    k_head1<<<N_GRAPHS, 64, 0, stream>>>(pooled, lin1W, lin1b, t1);
    k_head2<<<1, 64, 0, stream>>>(t1, bn_g, bn_b, hscsh);
    k_head3<<<N_GRAPHS, 64, 0, stream>>>(t1, hscsh, lin2W, lin2b, (float*)d_out);
}

// Round 7
// 1185.822 us; speedup vs baseline: 1.1922x; 1.1922x over previous
//
#include <hip/hip_runtime.h>

#define N_NODES 100000
#define N_EDGES 1600000
#define F_IN 128
#define HID 64
#define NLAYERS 4
#define N_GRAPHS 512
#define N_CLASSES 10
#define N_TILES ((N_NODES + 255) / 256)   // 391

typedef unsigned int uint_t;
typedef unsigned short ushort_t;

__device__ __forceinline__ float lo_bf(uint_t w) { return __uint_as_float(w << 16); }
__device__ __forceinline__ float hi_bf(uint_t w) { return __uint_as_float(w & 0xffff0000u); }
__device__ __forceinline__ ushort_t f2bf(float f) {
    uint_t u = __float_as_uint(f);
    u += 0x7fffu + ((u >> 16) & 1u);   // round-to-nearest-even
    return (ushort_t)(u >> 16);
}

// ---------------- CSR build ----------------
// degree + within-bucket rank in ONE atomic pass (rank store is coalesced)
__global__ __launch_bounds__(256) void k_degree_rank(const int* __restrict__ dst,
                                                     int* __restrict__ deg,
                                                     int* __restrict__ rank) {
    int base = blockIdx.x * 1024 + threadIdx.x;
    #pragma unroll
    for (int j = 0; j < 4; ++j) {
        int e = base + j * 256;
        if (e < N_EDGES) {
            int d = dst[e];
            int r = 0;
            if ((uint_t)d < (uint_t)N_NODES) r = atomicAdd(&deg[d], 1);
            rank[e] = r;
        }
    }
}

__global__ __launch_bounds__(256) void k_tilesum(const int* __restrict__ deg, int* __restrict__ bsum) {
    __shared__ int sh[256];
    int tid = threadIdx.x;
    int i = blockIdx.x * 256 + tid;
    sh[tid] = (i < N_NODES) ? deg[i] : 0;
    __syncthreads();
    for (int off = 128; off > 0; off >>= 1) {
        if (tid < off) sh[tid] += sh[tid + off];
        __syncthreads();
    }
    if (tid == 0) bsum[blockIdx.x] = sh[0];
}

__global__ __launch_bounds__(512) void k_tilescan(const int* __restrict__ bsum, int* __restrict__ boff) {
    __shared__ int sh[512];
    int tid = threadIdx.x;
    sh[tid] = (tid < N_TILES) ? bsum[tid] : 0;
    __syncthreads();
    for (int off = 1; off < 512; off <<= 1) {
        int t = (tid >= off) ? sh[tid - off] : 0;
        __syncthreads();
        sh[tid] += t;
        __syncthreads();
    }
    if (tid < N_TILES) boff[tid + 1] = sh[tid];
    if (tid == 0) boff[0] = 0;
}

__global__ __launch_bounds__(256) void k_tileapply(const int* __restrict__ deg, const int* __restrict__ boff,
                                                   int* __restrict__ row_ptr) {
    __shared__ int sh[256];
    int tid = threadIdx.x, b = blockIdx.x;
    int i = b * 256 + tid;
    sh[tid] = (i < N_NODES) ? deg[i] : 0;
    __syncthreads();
    for (int off = 1; off < 256; off <<= 1) {
        int t = (tid >= off) ? sh[tid - off] : 0;
        __syncthreads();
        sh[tid] += t;
        __syncthreads();
    }
    if (i < N_NODES) row_ptr[i + 1] = boff[b] + sh[tid];
    if (i == 0) row_ptr[0] = 0;
}

// pure gather+scatter, no atomics, fire-and-forget stores
__global__ __launch_bounds__(256) void k_fill(const int* __restrict__ src, const int* __restrict__ dst,
                                              const int* __restrict__ rank, const int* __restrict__ row_ptr,
                                              int* __restrict__ col_src) {
    int base = blockIdx.x * 1024 + threadIdx.x;
    #pragma unroll
    for (int j = 0; j < 4; ++j) {
        int e = base + j * 256;
        if (e < N_EDGES) {
            int d = dst[e];
            if ((uint_t)d >= (uint_t)N_NODES) continue;
            int pos = row_ptr[d] + rank[e];
            int s = src[e];
            if ((uint_t)s >= (uint_t)N_NODES) s = 0;
            if ((uint_t)pos < (uint_t)N_EDGES) col_src[pos] = s;
        }
    }
}

// ---------------- aggregation on bf16 y (dim 64) ----------------
// u[node] = (1+eps)*y[node] + sum_{in edges} y[src] + b1
// One wave per node; 32 lanes cover the 128B bf16 row (uint = 2 cols);
// 2 edges per wave-instruction (gid = lane>>5); guard-free main loop, 8 streams.
__global__ __launch_bounds__(256) void k_aggregate_u(const uint_t* __restrict__ ybf,
                                                     const int* __restrict__ row_ptr,
                                                     const int* __restrict__ col_src,
                                                     const float* __restrict__ eps, int layer,
                                                     const float* __restrict__ b1,
                                                     float* __restrict__ u) {
    int wid = threadIdx.x >> 6, lane = threadIdx.x & 63;
    int gid = lane >> 5, l5 = lane & 31;
    int node = blockIdx.x * 4 + wid;
    if (node >= N_NODES) return;
    float one_eps = 1.0f + eps[layer];
    int e0 = row_ptr[node], e1 = row_ptr[node + 1];
    if (e0 < 0) e0 = 0;
    if (e1 > N_EDGES) e1 = N_EDGES;
    if (e1 < e0) e1 = e0;
    int len = e1 - e0;
    int main_end = e0 + (len & ~15);

    float ax[8], ay[8];
    #pragma unroll
    for (int j = 0; j < 8; ++j) { ax[j] = 0.f; ay[j] = 0.f; }

    for (int eb = e0; eb < main_end; eb += 16) {
        #pragma unroll
        for (int j = 0; j < 8; ++j) {
            int s = col_src[eb + 2 * j + gid];
            if ((uint_t)s >= (uint_t)N_NODES) s = 0;
            uint_t w = ybf[(size_t)s * 32 + l5];
            ax[j] += lo_bf(w);
            ay[j] += hi_bf(w);
        }
    }
    for (int eb = main_end; eb < e1; eb += 2) {
        int ee = eb + gid;
        if (ee < e1) {
            int s = col_src[ee];
            if ((uint_t)s >= (uint_t)N_NODES) s = 0;
            uint_t w = ybf[(size_t)s * 32 + l5];
            ax[0] += lo_bf(w);
            ay[0] += hi_bf(w);
        }
    }
    float sx = ((ax[0] + ax[1]) + (ax[2] + ax[3])) + ((ax[4] + ax[5]) + (ax[6] + ax[7]));
    float sy = ((ay[0] + ay[1]) + (ay[2] + ay[3])) + ((ay[4] + ay[5]) + (ay[6] + ay[7]));
    sx += __shfl_xor(sx, 32, 64);
    sy += __shfl_xor(sy, 32, 64);
    if (gid == 0) {
        uint_t wself = ybf[(size_t)node * 32 + l5];
        float ox = sx + one_eps * lo_bf(wself) + b1[2 * l5 + 0];
        float oy = sy + one_eps * hi_bf(wself) + b1[2 * l5 + 1];
        ((float2*)u)[(size_t)node * 32 + l5] = make_float2(ox, oy);
    }
}

// ---------------- GEMM1: ybf[N x 64](bf16) = A[N x K](f32) @ W[K x 64]  (no bias) ----------------
template <int K>
__global__ __launch_bounds__(256) void k_gemm_f32(const float* __restrict__ A,
                                                  const float* __restrict__ W,
                                                  ushort_t* __restrict__ out) {
    __shared__ float Wl[K * 64];
    int tid = threadIdx.x;
    for (int i = tid; i < K * 64; i += 256) Wl[i] = W[i];
    __syncthreads();
    int col = tid & 63, wv = tid >> 6;
    int base = blockIdx.x * 16 + wv * 4;
    const float* A0 = A + (size_t)base * K;
    const float* A1 = A0 + K;
    const float* A2 = A1 + K;
    const float* A3 = A2 + K;
    float acc0 = 0.f, acc1 = 0.f, acc2 = 0.f, acc3 = 0.f;
    #pragma unroll 8
    for (int k = 0; k < K; ++k) {
        float wk = Wl[k * 64 + col];
        acc0 += A0[k] * wk;
        acc1 += A1[k] * wk;
        acc2 += A2[k] * wk;
        acc3 += A3[k] * wk;
    }
    out[(size_t)(base + 0) * 64 + col] = f2bf(acc0);
    out[(size_t)(base + 1) * 64 + col] = f2bf(acc1);
    out[(size_t)(base + 2) * 64 + col] = f2bf(acc2);
    out[(size_t)(base + 3) * 64 + col] = f2bf(acc3);
}

// ---------------- GEMM2 with BN+ReLU fused on the A-load ----------------
__global__ __launch_bounds__(256) void k_gemm_bn(const float* __restrict__ U,
                                                 const float* __restrict__ W,
                                                 const float* __restrict__ scsh,
                                                 const float* __restrict__ b2,
                                                 float* __restrict__ out) {
    __shared__ float Wl[64 * 64];
    __shared__ float Sc[64], Sh[64];
    int tid = threadIdx.x;
    for (int i = tid; i < 64 * 64; i += 256) Wl[i] = W[i];
    if (tid < 64) { Sc[tid] = scsh[tid]; Sh[tid] = scsh[64 + tid]; }
    __syncthreads();
    int col = tid & 63, wv = tid >> 6;
    float b = b2[col];
    int base = blockIdx.x * 16 + wv * 4;
    const float* A0 = U + (size_t)base * 64;
    const float* A1 = A0 + 64;
    const float* A2 = A1 + 64;
    const float* A3 = A2 + 64;
    float acc0 = b, acc1 = b, acc2 = b, acc3 = b;
    #pragma unroll 8
    for (int k = 0; k < 64; ++k) {
        float wk = Wl[k * 64 + col];
        float sck = Sc[k], shk = Sh[k];
        float v0 = fmaxf(fmaf(A0[k], sck, shk), 0.f);
        float v1 = fmaxf(fmaf(A1[k], sck, shk), 0.f);
        float v2 = fmaxf(fmaf(A2[k], sck, shk), 0.f);
        float v3 = fmaxf(fmaf(A3[k], sck, shk), 0.f);
        acc0 = fmaf(v0, wk, acc0);
        acc1 = fmaf(v1, wk, acc1);
        acc2 = fmaf(v2, wk, acc2);
        acc3 = fmaf(v3, wk, acc3);
    }
    acc0 = fmaxf(acc0, 0.f); acc1 = fmaxf(acc1, 0.f);
    acc2 = fmaxf(acc2, 0.f); acc3 = fmaxf(acc3, 0.f);
    out[(size_t)(base + 0) * 64 + col] = acc0;
    out[(size_t)(base + 1) * 64 + col] = acc1;
    out[(size_t)(base + 2) * 64 + col] = acc2;
    out[(size_t)(base + 3) * 64 + col] = acc3;
}

// ---------------- column stats over u [N_NODES x 64] ----------------
__global__ __launch_bounds__(256) void k_stats(const float* __restrict__ u, float* __restrict__ sums) {
    __shared__ float s1[256], s2[256];
    int tid = threadIdx.x;
    float a = 0.f, b = 0.f;
    for (size_t i = (size_t)blockIdx.x * 256 + tid; i < (size_t)N_NODES * 64; i += (size_t)gridDim.x * 256) {
        float v = u[i];
        a += v;
        b += v * v;
    }
    s1[tid] = a; s2[tid] = b;
    __syncthreads();
    if (tid < 128) { s1[tid] += s1[tid + 128]; s2[tid] += s2[tid + 128]; }
    __syncthreads();
    if (tid < 64) {
        atomicAdd(&sums[tid], s1[tid] + s1[tid + 64]);
        atomicAdd(&sums[64 + tid], s2[tid] + s2[tid + 64]);
    }
}

__global__ __launch_bounds__(64) void k_finalize(const float* __restrict__ sums,
                                                 const float* __restrict__ g,
                                                 const float* __restrict__ be,
                                                 float* __restrict__ scsh, float inv_n) {
    int c = threadIdx.x;
    float mean = sums[c] * inv_n;
    float var = sums[64 + c] * inv_n - mean * mean;
    if (var < 0.f) var = 0.f;
    float inv = rsqrtf(var + 1e-5f);
    float sc = inv * g[c];
    scsh[c] = sc;
    scsh[64 + c] = be[c] - mean * sc;
}

// ---------------- per-layer pooling (batch is sorted); 4 waves split the node range ----------------
__global__ __launch_bounds__(256) void k_pool1(const int* __restrict__ batch,
                                               const float* __restrict__ h,
                                               float* __restrict__ pooled, int layer) {
    __shared__ float red[256];
    int g = blockIdx.x, tid = threadIdx.x;
    int c = tid & 63, wv = tid >> 6;
    int lo = 0, hi = N_NODES;
    while (lo < hi) { int mid = (lo + hi) >> 1; if (batch[mid] < g) lo = mid + 1; else hi = mid; }
    int s = lo;
    lo = s; hi = N_NODES;
    while (lo < hi) { int mid = (lo + hi) >> 1; if (batch[mid] < g + 1) lo = mid + 1; else hi = mid; }
    int e = lo;
    int len = e - s;
    int chunk = (len + 3) >> 2;
    int ns = s + wv * chunk;
    int ne = ns + chunk; if (ne > e) ne = e;
    float a0 = 0.f, a1 = 0.f, a2 = 0.f, a3 = 0.f, a4 = 0.f, a5 = 0.f, a6 = 0.f, a7 = 0.f;
    int n = ns;
    for (; n + 8 <= ne; n += 8) {
        a0 += h[(size_t)(n + 0) * 64 + c];
        a1 += h[(size_t)(n + 1) * 64 + c];
        a2 += h[(size_t)(n + 2) * 64 + c];
        a3 += h[(size_t)(n + 3) * 64 + c];
        a4 += h[(size_t)(n + 4) * 64 + c];
        a5 += h[(size_t)(n + 5) * 64 + c];
        a6 += h[(size_t)(n + 6) * 64 + c];
        a7 += h[(size_t)(n + 7) * 64 + c];
    }
    for (; n < ne; ++n) a0 += h[(size_t)n * 64 + c];
    red[tid] = ((a0 + a1) + (a2 + a3)) + ((a4 + a5) + (a6 + a7));
    __syncthreads();
    if (wv == 0)
        pooled[g * 256 + layer * 64 + c] = (red[c] + red[64 + c]) + (red[128 + c] + red[192 + c]);
}

// ---------------- head ----------------
__global__ __launch_bounds__(64) void k_head1(const float* __restrict__ pooled,
                                              const float* __restrict__ W, const float* __restrict__ b,
                                              float* __restrict__ t1) {
    int g = blockIdx.x, lane = threadIdx.x;
    const float* p = pooled + g * 256;
    float acc = b[lane];
    for (int k = 0; k < 256; ++k) acc += p[k] * W[k * 64 + lane];
    t1[g * 64 + lane] = acc;
}

__global__ __launch_bounds__(64) void k_head2(const float* __restrict__ t1,
                                              const float* __restrict__ g_, const float* __restrict__ b_,
                                              float* __restrict__ scsh) {
    int c = threadIdx.x;
    float s = 0.f, q = 0.f;
    for (int r = 0; r < N_GRAPHS; ++r) {
        float v = t1[r * 64 + c];
        s += v; q += v * v;
    }
    float mean = s * (1.0f / N_GRAPHS);
    float var = q * (1.0f / N_GRAPHS) - mean * mean;
    if (var < 0.f) var = 0.f;
    float inv = rsqrtf(var + 1e-5f);
    float sc = inv * g_[c];
    scsh[c] = sc;
    scsh[64 + c] = b_[c] - mean * sc;
}

__global__ __launch_bounds__(64) void k_head3(const float* __restrict__ t1, const float* __restrict__ scsh,
                                              const float* __restrict__ W2, const float* __restrict__ b2,
                                              float* __restrict__ out) {
    __shared__ float v[64];
    __shared__ float o[16];
    int g = blockIdx.x, lane = threadIdx.x;
    float x = t1[g * 64 + lane] * scsh[lane] + scsh[64 + lane];
    v[lane] = fmaxf(x, 0.f);
    __syncthreads();
    if (lane < N_CLASSES) {
        float acc = b2[lane];
        for (int k = 0; k < 64; ++k) acc += v[k] * W2[k * N_CLASSES + lane];
        o[lane] = acc;
    }
    __syncthreads();
    if (lane < N_CLASSES) {
        float m = -1e30f;
        for (int k = 0; k < N_CLASSES; ++k) m = fmaxf(m, o[k]);
        float ssum = 0.f;
        for (int k = 0; k < N_CLASSES; ++k) ssum += expf(o[k] - m);
        out[g * N_CLASSES + lane] = o[lane] - m - logf(ssum);
    }
}

// ---------------- launch ----------------
extern "C" void kernel_launch(void* const* d_in, const int* in_sizes, int n_in,
                              void* d_out, int out_size, void* d_ws, size_t ws_size,
                              hipStream_t stream) {
    const float* x      = (const float*)d_in[0];
    const int*   ei     = (const int*)d_in[1];
    const int*   srcArr = ei;
    const int*   dstArr = ei + N_EDGES;
    const int*   batch  = (const int*)d_in[2];
    const float* eps    = (const float*)d_in[3];
    const float* W1_0   = (const float*)d_in[4];
    const float* b1_0   = (const float*)d_in[5];
    const float* g_0    = (const float*)d_in[6];
    const float* be_0   = (const float*)d_in[7];
    const float* W2_0   = (const float*)d_in[8];
    const float* b2_0   = (const float*)d_in[9];
    const float* W1_r   = (const float*)d_in[10];
    const float* b1_r   = (const float*)d_in[11];
    const float* g_r    = (const float*)d_in[12];
    const float* be_r   = (const float*)d_in[13];
    const float* W2_r   = (const float*)d_in[14];
    const float* b2_r   = (const float*)d_in[15];
    const float* lin1W  = (const float*)d_in[16];
    const float* lin1b  = (const float*)d_in[17];
    const float* bn_g   = (const float*)d_in[18];
    const float* bn_b   = (const float*)d_in[19];
    const float* lin2W  = (const float*)d_in[20];
    const float* lin2b  = (const float*)d_in[21];

    char* ws = (char*)d_ws;
    auto alloc = [&](size_t bytes) {
        char* p = ws;
        ws += (bytes + 255) & ~(size_t)255;
        return p;
    };
    int*      deg     = (int*)alloc((size_t)N_NODES * 4);
    int*      row_ptr = (int*)alloc(((size_t)N_NODES + 1) * 4);
    int*      rank    = (int*)alloc((size_t)N_EDGES * 4);
    int*      bsum    = (int*)alloc((size_t)N_TILES * 4);
    int*      boff    = (int*)alloc(((size_t)N_TILES + 1) * 4);
    int*      col_src = (int*)alloc((size_t)N_EDGES * 4);
    ushort_t* ybf     = (ushort_t*)alloc((size_t)N_NODES * 64 * 2);
    float*    u       = (float*)alloc((size_t)N_NODES * 64 * 4);
    float*    hA      = (float*)alloc((size_t)N_NODES * 64 * 4);
    float*    hB      = (float*)alloc((size_t)N_NODES * 64 * 4);
    float*    statsA  = (float*)alloc(NLAYERS * 128 * 4);
    float*    scsh    = (float*)alloc(NLAYERS * 128 * 4);
    float*    pooled  = (float*)alloc((size_t)N_GRAPHS * 256 * 4);
    float*    t1      = (float*)alloc((size_t)N_GRAPHS * 64 * 4);
    float*    hscsh   = (float*)alloc(128 * 4);

    hipMemsetAsync(deg, 0, (size_t)N_NODES * 4, stream);
    hipMemsetAsync(statsA, 0, NLAYERS * 128 * 4, stream);

    const int e4_grid = (N_EDGES + 1023) / 1024;
    k_degree_rank<<<e4_grid, 256, 0, stream>>>(dstArr, deg, rank);
    k_tilesum<<<N_TILES, 256, 0, stream>>>(deg, bsum);
    k_tilescan<<<1, 512, 0, stream>>>(bsum, boff);
    k_tileapply<<<N_TILES, 256, 0, stream>>>(deg, boff, row_ptr);
    k_fill<<<e4_grid, 256, 0, stream>>>(srcArr, dstArr, rank, row_ptr, col_src);

    const int agg_grid  = N_NODES / 4;            // 25000, exact
    const int gemm_grid = N_NODES / 16;           // 6250, exact

    const float* hin = x;
    float* hping[2] = {hA, hB};
    for (int l = 0; l < NLAYERS; ++l) {
        const float *W1, *b1, *gg, *be, *W2, *b2;
        if (l == 0) { W1 = W1_0; b1 = b1_0; gg = g_0; be = be_0; W2 = W2_0; b2 = b2_0; }
        else {
            W1 = W1_r + (size_t)(l - 1) * 64 * 64;
            b1 = b1_r + (size_t)(l - 1) * 64;
            gg = g_r  + (size_t)(l - 1) * 64;
            be = be_r + (size_t)(l - 1) * 64;
            W2 = W2_r + (size_t)(l - 1) * 64 * 64;
            b2 = b2_r + (size_t)(l - 1) * 64;
        }
        float* hout = hping[l & 1];
        // y = bf16(h @ W1)   (bias folded into aggregate)
        if (l == 0) k_gemm_f32<128><<<gemm_grid, 256, 0, stream>>>(hin, W1, ybf);
        else        k_gemm_f32<64><<<gemm_grid, 256, 0, stream>>>(hin, W1, ybf);
        // u = (1+eps)*y + sum y[src] + b1
        k_aggregate_u<<<agg_grid, 256, 0, stream>>>((const uint_t*)ybf, row_ptr, col_src, eps, l, b1, u);
        k_stats<<<256, 256, 0, stream>>>(u, statsA + l * 128);
        k_finalize<<<1, 64, 0, stream>>>(statsA + l * 128, gg, be, scsh + l * 128, 1.0f / N_NODES);
        // h = relu( relu(bn(u)) @ W2 + b2 )
        k_gemm_bn<<<gemm_grid, 256, 0, stream>>>(u, W2, scsh + l * 128, b2, hout);
        k_pool1<<<N_GRAPHS, 256, 0, stream>>>(batch, hout, pooled, l);
        hin = hout;
    }

    k_head1<<<N_GRAPHS, 64, 0, stream>>>(pooled, lin1W, lin1b, t1);
    k_head2<<<1, 64, 0, stream>>>(t1, bn_g, bn_b, hscsh);
    k_head3<<<N_GRAPHS, 64, 0, stream>>>(t1, hscsh, lin2W, lin2b, (float*)d_out);
}

// Round 8
// 852.895 us; speedup vs baseline: 1.6575x; 1.3903x over previous
//
#include <hip/hip_runtime.h>

#define N_NODES 100000
#define N_EDGES 1600000
#define F_IN 128
#define HID 64
#define NLAYERS 4
#define N_GRAPHS 512
#define N_CLASSES 10
#define N_TILES ((N_NODES + 255) / 256)   // 391

typedef unsigned int uint_t;
typedef unsigned short ushort_t;

__device__ __forceinline__ float lo_bf(uint_t w) { return __uint_as_float(w << 16); }
__device__ __forceinline__ float hi_bf(uint_t w) { return __uint_as_float(w & 0xffff0000u); }
__device__ __forceinline__ ushort_t f2bf(float f) {
    uint_t u = __float_as_uint(f);
    u += 0x7fffu + ((u >> 16) & 1u);   // round-to-nearest-even
    return (ushort_t)(u >> 16);
}

// ---------------- CSR build ----------------
__global__ __launch_bounds__(256) void k_degree_rank(const int* __restrict__ dst,
                                                     int* __restrict__ deg,
                                                     int* __restrict__ rank) {
    int base = blockIdx.x * 1024 + threadIdx.x;
    #pragma unroll
    for (int j = 0; j < 4; ++j) {
        int e = base + j * 256;
        if (e < N_EDGES) {
            int d = dst[e];
            int r = 0;
            if ((uint_t)d < (uint_t)N_NODES) r = atomicAdd(&deg[d], 1);
            rank[e] = r;
        }
    }
}

__global__ __launch_bounds__(256) void k_tilesum(const int* __restrict__ deg, int* __restrict__ bsum) {
    __shared__ int sh[256];
    int tid = threadIdx.x;
    int i = blockIdx.x * 256 + tid;
    sh[tid] = (i < N_NODES) ? deg[i] : 0;
    __syncthreads();
    for (int off = 128; off > 0; off >>= 1) {
        if (tid < off) sh[tid] += sh[tid + off];
        __syncthreads();
    }
    if (tid == 0) bsum[blockIdx.x] = sh[0];
}

__global__ __launch_bounds__(512) void k_tilescan(const int* __restrict__ bsum, int* __restrict__ boff) {
    __shared__ int sh[512];
    int tid = threadIdx.x;
    sh[tid] = (tid < N_TILES) ? bsum[tid] : 0;
    __syncthreads();
    for (int off = 1; off < 512; off <<= 1) {
        int t = (tid >= off) ? sh[tid - off] : 0;
        __syncthreads();
        sh[tid] += t;
        __syncthreads();
    }
    if (tid < N_TILES) boff[tid + 1] = sh[tid];
    if (tid == 0) boff[0] = 0;
}

__global__ __launch_bounds__(256) void k_tileapply(const int* __restrict__ deg, const int* __restrict__ boff,
                                                   int* __restrict__ row_ptr) {
    __shared__ int sh[256];
    int tid = threadIdx.x, b = blockIdx.x;
    int i = b * 256 + tid;
    sh[tid] = (i < N_NODES) ? deg[i] : 0;
    __syncthreads();
    for (int off = 1; off < 256; off <<= 1) {
        int t = (tid >= off) ? sh[tid - off] : 0;
        __syncthreads();
        sh[tid] += t;
        __syncthreads();
    }
    if (i < N_NODES) row_ptr[i + 1] = boff[b] + sh[tid];
    if (i == 0) row_ptr[0] = 0;
}

__global__ __launch_bounds__(256) void k_fill(const int* __restrict__ src, const int* __restrict__ dst,
                                              const int* __restrict__ rank, const int* __restrict__ row_ptr,
                                              int* __restrict__ col_src) {
    int base = blockIdx.x * 1024 + threadIdx.x;
    #pragma unroll
    for (int j = 0; j < 4; ++j) {
        int e = base + j * 256;
        if (e < N_EDGES) {
            int d = dst[e];
            if ((uint_t)d >= (uint_t)N_NODES) continue;
            int pos = row_ptr[d] + rank[e];
            int s = src[e];
            if ((uint_t)s >= (uint_t)N_NODES) s = 0;
            if ((uint_t)pos < (uint_t)N_EDGES) col_src[pos] = s;
        }
    }
}

// ---------------- aggregation on bf16 y (dim 64) ----------------
__global__ __launch_bounds__(256) void k_aggregate_u(const uint_t* __restrict__ ybf,
                                                     const int* __restrict__ row_ptr,
                                                     const int* __restrict__ col_src,
                                                     const float* __restrict__ eps, int layer,
                                                     const float* __restrict__ b1,
                                                     float* __restrict__ u) {
    int wid = threadIdx.x >> 6, lane = threadIdx.x & 63;
    int gid = lane >> 5, l5 = lane & 31;
    int node = blockIdx.x * 4 + wid;
    if (node >= N_NODES) return;
    float one_eps = 1.0f + eps[layer];
    int e0 = row_ptr[node], e1 = row_ptr[node + 1];
    if (e0 < 0) e0 = 0;
    if (e1 > N_EDGES) e1 = N_EDGES;
    if (e1 < e0) e1 = e0;
    int len = e1 - e0;
    int main_end = e0 + (len & ~15);

    float ax[8], ay[8];
    #pragma unroll
    for (int j = 0; j < 8; ++j) { ax[j] = 0.f; ay[j] = 0.f; }

    for (int eb = e0; eb < main_end; eb += 16) {
        #pragma unroll
        for (int j = 0; j < 8; ++j) {
            int s = col_src[eb + 2 * j + gid];
            if ((uint_t)s >= (uint_t)N_NODES) s = 0;
            uint_t w = ybf[(size_t)s * 32 + l5];
            ax[j] += lo_bf(w);
            ay[j] += hi_bf(w);
        }
    }
    for (int eb = main_end; eb < e1; eb += 2) {
        int ee = eb + gid;
        if (ee < e1) {
            int s = col_src[ee];
            if ((uint_t)s >= (uint_t)N_NODES) s = 0;
            uint_t w = ybf[(size_t)s * 32 + l5];
            ax[0] += lo_bf(w);
            ay[0] += hi_bf(w);
        }
    }
    float sx = ((ax[0] + ax[1]) + (ax[2] + ax[3])) + ((ax[4] + ax[5]) + (ax[6] + ax[7]));
    float sy = ((ay[0] + ay[1]) + (ay[2] + ay[3])) + ((ay[4] + ay[5]) + (ay[6] + ay[7]));
    sx += __shfl_xor(sx, 32, 64);
    sy += __shfl_xor(sy, 32, 64);
    if (gid == 0) {
        uint_t wself = ybf[(size_t)node * 32 + l5];
        float ox = sx + one_eps * lo_bf(wself) + b1[2 * l5 + 0];
        float oy = sy + one_eps * hi_bf(wself) + b1[2 * l5 + 1];
        ((float2*)u)[(size_t)node * 32 + l5] = make_float2(ox, oy);
    }
}

// ---------------- GEMM1: ybf[N x 64](bf16) = A[N x K](f32) @ W[K x 64]  (no bias) ----------------
// LDS-tiled: block = 64 rows x 64 cols; A-tile in LDS (row stride K+4), W in LDS.
// Each thread computes a 4x4 register tile.
template <int K>
__global__ __launch_bounds__(256) void k_gemm1(const float* __restrict__ A,
                                               const float* __restrict__ W,
                                               ushort_t* __restrict__ out) {
    constexpr int KP = K + 4;
    constexpr int KQ = K / 4;
    __shared__ float Al[64 * KP];
    __shared__ float Wl[K * 64];
    int tid = threadIdx.x;
    int base = blockIdx.x * 64;

    for (int i = tid; i < K * 16; i += 256)
        ((float4*)Wl)[i] = ((const float4*)W)[i];

    if (base + 64 <= N_NODES) {
        const float4* Ag = (const float4*)(A + (size_t)base * K);
        for (int i = tid; i < 16 * K; i += 256) {
            int row = i / KQ, kk = (i % KQ) * 4;
            float4 v = Ag[i];
            *(float4*)&Al[row * KP + kk] = v;
        }
    } else {
        for (int i = tid; i < 16 * K; i += 256) {
            int row = i / KQ, kk = (i % KQ) * 4;
            int grow = base + row; if (grow >= N_NODES) grow = N_NODES - 1;
            float4 v = ((const float4*)(A + (size_t)grow * K))[i % KQ];
            *(float4*)&Al[row * KP + kk] = v;
        }
    }
    __syncthreads();

    int ct = (tid & 15) * 4;
    int rb = (tid >> 4) * 4;
    float4 acc0 = {0.f, 0.f, 0.f, 0.f}, acc1 = acc0, acc2 = acc0, acc3 = acc0;
    const float* A0 = &Al[(rb + 0) * KP];
    const float* A1 = &Al[(rb + 1) * KP];
    const float* A2 = &Al[(rb + 2) * KP];
    const float* A3 = &Al[(rb + 3) * KP];
    #pragma unroll 4
    for (int k = 0; k < K; ++k) {
        float4 w = *(const float4*)&Wl[k * 64 + ct];
        float a0 = A0[k], a1 = A1[k], a2 = A2[k], a3 = A3[k];
        acc0.x = fmaf(a0, w.x, acc0.x); acc0.y = fmaf(a0, w.y, acc0.y);
        acc0.z = fmaf(a0, w.z, acc0.z); acc0.w = fmaf(a0, w.w, acc0.w);
        acc1.x = fmaf(a1, w.x, acc1.x); acc1.y = fmaf(a1, w.y, acc1.y);
        acc1.z = fmaf(a1, w.z, acc1.z); acc1.w = fmaf(a1, w.w, acc1.w);
        acc2.x = fmaf(a2, w.x, acc2.x); acc2.y = fmaf(a2, w.y, acc2.y);
        acc2.z = fmaf(a2, w.z, acc2.z); acc2.w = fmaf(a2, w.w, acc2.w);
        acc3.x = fmaf(a3, w.x, acc3.x); acc3.y = fmaf(a3, w.y, acc3.y);
        acc3.z = fmaf(a3, w.z, acc3.z); acc3.w = fmaf(a3, w.w, acc3.w);
    }

    float4 accs[4] = {acc0, acc1, acc2, acc3};
    #pragma unroll
    for (int r = 0; r < 4; ++r) {
        int row = base + rb + r;
        if (row < N_NODES) {
            ushort4 o;
            o.x = f2bf(accs[r].x); o.y = f2bf(accs[r].y);
            o.z = f2bf(accs[r].z); o.w = f2bf(accs[r].w);
            *(ushort4*)&out[(size_t)row * 64 + ct] = o;
        }
    }
}

// ---------------- GEMM2: h = relu( relu(bn(u)) @ W2 + b2 ), BN fused at staging ----------------
__global__ __launch_bounds__(256) void k_gemm_bn(const float* __restrict__ U,
                                                 const float* __restrict__ W,
                                                 const float* __restrict__ scsh,
                                                 const float* __restrict__ b2,
                                                 float* __restrict__ out) {
    constexpr int K = 64, KP = 68, KQ = 16;
    __shared__ float Al[64 * KP];
    __shared__ float Wl[K * 64];
    int tid = threadIdx.x;
    int base = blockIdx.x * 64;

    for (int i = tid; i < K * 16; i += 256)
        ((float4*)Wl)[i] = ((const float4*)W)[i];

    {
        const float4* sc4 = (const float4*)scsh;        // [0..15] sc, [16..31] sh
        bool full = (base + 64 <= N_NODES);
        for (int i = tid; i < 16 * K; i += 256) {
            int row = i / KQ, kq = i % KQ, kk = kq * 4;
            int grow = base + row;
            if (!full && grow >= N_NODES) grow = N_NODES - 1;
            float4 v = ((const float4*)(U + (size_t)grow * K))[kq];
            float4 sc = sc4[kq], sh = sc4[16 + kq];
            v.x = fmaxf(fmaf(v.x, sc.x, sh.x), 0.f);
            v.y = fmaxf(fmaf(v.y, sc.y, sh.y), 0.f);
            v.z = fmaxf(fmaf(v.z, sc.z, sh.z), 0.f);
            v.w = fmaxf(fmaf(v.w, sc.w, sh.w), 0.f);
            *(float4*)&Al[row * KP + kk] = v;
        }
    }
    __syncthreads();

    int ct = (tid & 15) * 4;
    int rb = (tid >> 4) * 4;
    float4 acc0 = {0.f, 0.f, 0.f, 0.f}, acc1 = acc0, acc2 = acc0, acc3 = acc0;
    const float* A0 = &Al[(rb + 0) * KP];
    const float* A1 = &Al[(rb + 1) * KP];
    const float* A2 = &Al[(rb + 2) * KP];
    const float* A3 = &Al[(rb + 3) * KP];
    #pragma unroll 4
    for (int k = 0; k < K; ++k) {
        float4 w = *(const float4*)&Wl[k * 64 + ct];
        float a0 = A0[k], a1 = A1[k], a2 = A2[k], a3 = A3[k];
        acc0.x = fmaf(a0, w.x, acc0.x); acc0.y = fmaf(a0, w.y, acc0.y);
        acc0.z = fmaf(a0, w.z, acc0.z); acc0.w = fmaf(a0, w.w, acc0.w);
        acc1.x = fmaf(a1, w.x, acc1.x); acc1.y = fmaf(a1, w.y, acc1.y);
        acc1.z = fmaf(a1, w.z, acc1.z); acc1.w = fmaf(a1, w.w, acc1.w);
        acc2.x = fmaf(a2, w.x, acc2.x); acc2.y = fmaf(a2, w.y, acc2.y);
        acc2.z = fmaf(a2, w.z, acc2.z); acc2.w = fmaf(a2, w.w, acc2.w);
        acc3.x = fmaf(a3, w.x, acc3.x); acc3.y = fmaf(a3, w.y, acc3.y);
        acc3.z = fmaf(a3, w.z, acc3.z); acc3.w = fmaf(a3, w.w, acc3.w);
    }

    float4 bb = *(const float4*)&b2[ct];
    float4 accs[4] = {acc0, acc1, acc2, acc3};
    #pragma unroll
    for (int r = 0; r < 4; ++r) {
        int row = base + rb + r;
        if (row < N_NODES) {
            float4 o;
            o.x = fmaxf(accs[r].x + bb.x, 0.f);
            o.y = fmaxf(accs[r].y + bb.y, 0.f);
            o.z = fmaxf(accs[r].z + bb.z, 0.f);
            o.w = fmaxf(accs[r].w + bb.w, 0.f);
            *(float4*)&out[(size_t)row * 64 + ct] = o;
        }
    }
}

// ---------------- column stats over u [N_NODES x 64] ----------------
__global__ __launch_bounds__(256) void k_stats(const float* __restrict__ u, float* __restrict__ sums) {
    __shared__ float s1[256], s2[256];
    int tid = threadIdx.x;
    float a = 0.f, b = 0.f;
    for (size_t i = (size_t)blockIdx.x * 256 + tid; i < (size_t)N_NODES * 64; i += (size_t)gridDim.x * 256) {
        float v = u[i];
        a += v;
        b += v * v;
    }
    s1[tid] = a; s2[tid] = b;
    __syncthreads();
    if (tid < 128) { s1[tid] += s1[tid + 128]; s2[tid] += s2[tid + 128]; }
    __syncthreads();
    if (tid < 64) {
        atomicAdd(&sums[tid], s1[tid] + s1[tid + 64]);
        atomicAdd(&sums[64 + tid], s2[tid] + s2[tid + 64]);
    }
}

__global__ __launch_bounds__(64) void k_finalize(const float* __restrict__ sums,
                                                 const float* __restrict__ g,
                                                 const float* __restrict__ be,
                                                 float* __restrict__ scsh, float inv_n) {
    int c = threadIdx.x;
    float mean = sums[c] * inv_n;
    float var = sums[64 + c] * inv_n - mean * mean;
    if (var < 0.f) var = 0.f;
    float inv = rsqrtf(var + 1e-5f);
    float sc = inv * g[c];
    scsh[c] = sc;
    scsh[64 + c] = be[c] - mean * sc;
}

// ---------------- per-layer pooling (batch is sorted); 4 waves split the node range ----------------
__global__ __launch_bounds__(256) void k_pool1(const int* __restrict__ batch,
                                               const float* __restrict__ h,
                                               float* __restrict__ pooled, int layer) {
    __shared__ float red[256];
    int g = blockIdx.x, tid = threadIdx.x;
    int c = tid & 63, wv = tid >> 6;
    int lo = 0, hi = N_NODES;
    while (lo < hi) { int mid = (lo + hi) >> 1; if (batch[mid] < g) lo = mid + 1; else hi = mid; }
    int s = lo;
    lo = s; hi = N_NODES;
    while (lo < hi) { int mid = (lo + hi) >> 1; if (batch[mid] < g + 1) lo = mid + 1; else hi = mid; }
    int e = lo;
    int len = e - s;
    int chunk = (len + 3) >> 2;
    int ns = s + wv * chunk;
    int ne = ns + chunk; if (ne > e) ne = e;
    float a0 = 0.f, a1 = 0.f, a2 = 0.f, a3 = 0.f, a4 = 0.f, a5 = 0.f, a6 = 0.f, a7 = 0.f;
    int n = ns;
    for (; n + 8 <= ne; n += 8) {
        a0 += h[(size_t)(n + 0) * 64 + c];
        a1 += h[(size_t)(n + 1) * 64 + c];
        a2 += h[(size_t)(n + 2) * 64 + c];
        a3 += h[(size_t)(n + 3) * 64 + c];
        a4 += h[(size_t)(n + 4) * 64 + c];
        a5 += h[(size_t)(n + 5) * 64 + c];
        a6 += h[(size_t)(n + 6) * 64 + c];
        a7 += h[(size_t)(n + 7) * 64 + c];
    }
    for (; n < ne; ++n) a0 += h[(size_t)n * 64 + c];
    red[tid] = ((a0 + a1) + (a2 + a3)) + ((a4 + a5) + (a6 + a7));
    __syncthreads();
    if (wv == 0)
        pooled[g * 256 + layer * 64 + c] = (red[c] + red[64 + c]) + (red[128 + c] + red[192 + c]);
}

// ---------------- head ----------------
__global__ __launch_bounds__(64) void k_head1(const float* __restrict__ pooled,
                                              const float* __restrict__ W, const float* __restrict__ b,
                                              float* __restrict__ t1) {
    int g = blockIdx.x, lane = threadIdx.x;
    const float* p = pooled + g * 256;
    float acc = b[lane];
    for (int k = 0; k < 256; ++k) acc += p[k] * W[k * 64 + lane];
    t1[g * 64 + lane] = acc;
}

__global__ __launch_bounds__(64) void k_head2(const float* __restrict__ t1,
                                              const float* __restrict__ g_, const float* __restrict__ b_,
                                              float* __restrict__ scsh) {
    int c = threadIdx.x;
    float s = 0.f, q = 0.f;
    for (int r = 0; r < N_GRAPHS; ++r) {
        float v = t1[r * 64 + c];
        s += v; q += v * v;
    }
    float mean = s * (1.0f / N_GRAPHS);
    float var = q * (1.0f / N_GRAPHS) - mean * mean;
    if (var < 0.f) var = 0.f;
    float inv = rsqrtf(var + 1e-5f);
    float sc = inv * g_[c];
    scsh[c] = sc;
    scsh[64 + c] = b_[c] - mean * sc;
}

__global__ __launch_bounds__(64) void k_head3(const float* __restrict__ t1, const float* __restrict__ scsh,
                                              const float* __restrict__ W2, const float* __restrict__ b2,
                                              float* __restrict__ out) {
    __shared__ float v[64];
    __shared__ float o[16];
    int g = blockIdx.x, lane = threadIdx.x;
    float x = t1[g * 64 + lane] * scsh[lane] + scsh[64 + lane];
    v[lane] = fmaxf(x, 0.f);
    __syncthreads();
    if (lane < N_CLASSES) {
        float acc = b2[lane];
        for (int k = 0; k < 64; ++k) acc += v[k] * W2[k * N_CLASSES + lane];
        o[lane] = acc;
    }
    __syncthreads();
    if (lane < N_CLASSES) {
        float m = -1e30f;
        for (int k = 0; k < N_CLASSES; ++k) m = fmaxf(m, o[k]);
        float ssum = 0.f;
        for (int k = 0; k < N_CLASSES; ++k) ssum += expf(o[k] - m);
        out[g * N_CLASSES + lane] = o[lane] - m - logf(ssum);
    }
}

// ---------------- launch ----------------
extern "C" void kernel_launch(void* const* d_in, const int* in_sizes, int n_in,
                              void* d_out, int out_size, void* d_ws, size_t ws_size,
                              hipStream_t stream) {
    const float* x      = (const float*)d_in[0];
    const int*   ei     = (const int*)d_in[1];
    const int*   srcArr = ei;
    const int*   dstArr = ei + N_EDGES;
    const int*   batch  = (const int*)d_in[2];
    const float* eps    = (const float*)d_in[3];
    const float* W1_0   = (const float*)d_in[4];
    const float* b1_0   = (const float*)d_in[5];
    const float* g_0    = (const float*)d_in[6];
    const float* be_0   = (const float*)d_in[7];
    const float* W2_0   = (const float*)d_in[8];
    const float* b2_0   = (const float*)d_in[9];
    const float* W1_r   = (const float*)d_in[10];
    const float* b1_r   = (const float*)d_in[11];
    const float* g_r    = (const float*)d_in[12];
    const float* be_r   = (const float*)d_in[13];
    const float* W2_r   = (const float*)d_in[14];
    const float* b2_r   = (const float*)d_in[15];
    const float* lin1W  = (const float*)d_in[16];
    const float* lin1b  = (const float*)d_in[17];
    const float* bn_g   = (const float*)d_in[18];
    const float* bn_b   = (const float*)d_in[19];
    const float* lin2W  = (const float*)d_in[20];
    const float* lin2b  = (const float*)d_in[21];

    char* ws = (char*)d_ws;
    auto alloc = [&](size_t bytes) {
        char* p = ws;
        ws += (bytes + 255) & ~(size_t)255;
        return p;
    };
    int*      deg     = (int*)alloc((size_t)N_NODES * 4);
    int*      row_ptr = (int*)alloc(((size_t)N_NODES + 1) * 4);
    int*      rank    = (int*)alloc((size_t)N_EDGES * 4);
    int*      bsum    = (int*)alloc((size_t)N_TILES * 4);
    int*      boff    = (int*)alloc(((size_t)N_TILES + 1) * 4);
    int*      col_src = (int*)alloc((size_t)N_EDGES * 4);
    ushort_t* ybf     = (ushort_t*)alloc((size_t)N_NODES * 64 * 2);
    float*    u       = (float*)alloc((size_t)N_NODES * 64 * 4);
    float*    hA      = (float*)alloc((size_t)N_NODES * 64 * 4);
    float*    hB      = (float*)alloc((size_t)N_NODES * 64 * 4);
    float*    statsA  = (float*)alloc(NLAYERS * 128 * 4);
    float*    scsh    = (float*)alloc(NLAYERS * 128 * 4);
    float*    pooled  = (float*)alloc((size_t)N_GRAPHS * 256 * 4);
    float*    t1      = (float*)alloc((size_t)N_GRAPHS * 64 * 4);
    float*    hscsh   = (float*)alloc(128 * 4);

    hipMemsetAsync(deg, 0, (size_t)N_NODES * 4, stream);
    hipMemsetAsync(statsA, 0, NLAYERS * 128 * 4, stream);

    const int e4_grid = (N_EDGES + 1023) / 1024;
    k_degree_rank<<<e4_grid, 256, 0, stream>>>(dstArr, deg, rank);
    k_tilesum<<<N_TILES, 256, 0, stream>>>(deg, bsum);
    k_tilescan<<<1, 512, 0, stream>>>(bsum, boff);
    k_tileapply<<<N_TILES, 256, 0, stream>>>(deg, boff, row_ptr);
    k_fill<<<e4_grid, 256, 0, stream>>>(srcArr, dstArr, rank, row_ptr, col_src);

    const int agg_grid  = N_NODES / 4;              // 25000, exact
    const int gemm_grid = (N_NODES + 63) / 64;      // 1563

    const float* hin = x;
    float* hping[2] = {hA, hB};
    for (int l = 0; l < NLAYERS; ++l) {
        const float *W1, *b1, *gg, *be, *W2, *b2;
        if (l == 0) { W1 = W1_0; b1 = b1_0; gg = g_0; be = be_0; W2 = W2_0; b2 = b2_0; }
        else {
            W1 = W1_r + (size_t)(l - 1) * 64 * 64;
            b1 = b1_r + (size_t)(l - 1) * 64;
            gg = g_r  + (size_t)(l - 1) * 64;
            be = be_r + (size_t)(l - 1) * 64;
            W2 = W2_r + (size_t)(l - 1) * 64 * 64;
            b2 = b2_r + (size_t)(l - 1) * 64;
        }
        float* hout = hping[l & 1];
        // y = bf16(h @ W1)   (bias folded into aggregate)
        if (l == 0) k_gemm1<128><<<gemm_grid, 256, 0, stream>>>(hin, W1, ybf);
        else        k_gemm1<64><<<gemm_grid, 256, 0, stream>>>(hin, W1, ybf);
        // u = (1+eps)*y + sum y[src] + b1
        k_aggregate_u<<<agg_grid, 256, 0, stream>>>((const uint_t*)ybf, row_ptr, col_src, eps, l, b1, u);
        k_stats<<<256, 256, 0, stream>>>(u, statsA + l * 128);
        k_finalize<<<1, 64, 0, stream>>>(statsA + l * 128, gg, be, scsh + l * 128, 1.0f / N_NODES);
        // h = relu( relu(bn(u)) @ W2 + b2 )
        k_gemm_bn<<<gemm_grid, 256, 0, stream>>>(u, W2, scsh + l * 128, b2, hout);
        k_pool1<<<N_GRAPHS, 256, 0, stream>>>(batch, hout, pooled, l);
        hin = hout;
    }

    k_head1<<<N_GRAPHS, 64, 0, stream>>>(pooled, lin1W, lin1b, t1);
    k_head2<<<1, 64, 0, stream>>>(t1, bn_g, bn_b, hscsh);
    k_head3<<<N_GRAPHS, 64, 0, stream>>>(t1, hscsh, lin2W, lin2b, (float*)d_out);
}

// Round 9
// 792.569 us; speedup vs baseline: 1.7837x; 1.0761x over previous
//
#include <hip/hip_runtime.h>

#define N_NODES 100000
#define N_EDGES 1600000
#define F_IN 128
#define HID 64
#define NLAYERS 4
#define N_GRAPHS 512
#define N_CLASSES 10
#define N_TILES ((N_NODES + 255) / 256)   // 391

typedef unsigned int uint_t;
typedef unsigned short ushort_t;

__device__ __forceinline__ float lo_bf(uint_t w) { return __uint_as_float(w << 16); }
__device__ __forceinline__ float hi_bf(uint_t w) { return __uint_as_float(w & 0xffff0000u); }
__device__ __forceinline__ ushort_t f2bf(float f) {
    uint_t u = __float_as_uint(f);
    u += 0x7fffu + ((u >> 16) & 1u);   // round-to-nearest-even
    return (ushort_t)(u >> 16);
}

// ---------------- CSR build ----------------
__global__ __launch_bounds__(256) void k_degree_rank(const int* __restrict__ dst,
                                                     int* __restrict__ deg,
                                                     int* __restrict__ rank) {
    int base = blockIdx.x * 1024 + threadIdx.x;
    #pragma unroll
    for (int j = 0; j < 4; ++j) {
        int e = base + j * 256;
        if (e < N_EDGES) {
            int d = dst[e];
            int r = 0;
            if ((uint_t)d < (uint_t)N_NODES) r = atomicAdd(&deg[d], 1);
            rank[e] = r;
        }
    }
}

__global__ __launch_bounds__(256) void k_tilesum(const int* __restrict__ deg, int* __restrict__ bsum) {
    __shared__ int sh[256];
    int tid = threadIdx.x;
    int i = blockIdx.x * 256 + tid;
    sh[tid] = (i < N_NODES) ? deg[i] : 0;
    __syncthreads();
    for (int off = 128; off > 0; off >>= 1) {
        if (tid < off) sh[tid] += sh[tid + off];
        __syncthreads();
    }
    if (tid == 0) bsum[blockIdx.x] = sh[0];
}

__global__ __launch_bounds__(512) void k_tilescan(const int* __restrict__ bsum, int* __restrict__ boff) {
    __shared__ int sh[512];
    int tid = threadIdx.x;
    sh[tid] = (tid < N_TILES) ? bsum[tid] : 0;
    __syncthreads();
    for (int off = 1; off < 512; off <<= 1) {
        int t = (tid >= off) ? sh[tid - off] : 0;
        __syncthreads();
        sh[tid] += t;
        __syncthreads();
    }
    if (tid < N_TILES) boff[tid + 1] = sh[tid];
    if (tid == 0) boff[0] = 0;
}

__global__ __launch_bounds__(256) void k_tileapply(const int* __restrict__ deg, const int* __restrict__ boff,
                                                   int* __restrict__ row_ptr) {
    __shared__ int sh[256];
    int tid = threadIdx.x, b = blockIdx.x;
    int i = b * 256 + tid;
    sh[tid] = (i < N_NODES) ? deg[i] : 0;
    __syncthreads();
    for (int off = 1; off < 256; off <<= 1) {
        int t = (tid >= off) ? sh[tid - off] : 0;
        __syncthreads();
        sh[tid] += t;
        __syncthreads();
    }
    if (i < N_NODES) row_ptr[i + 1] = boff[b] + sh[tid];
    if (i == 0) row_ptr[0] = 0;
}

__global__ __launch_bounds__(256) void k_fill(const int* __restrict__ src, const int* __restrict__ dst,
                                              const int* __restrict__ rank, const int* __restrict__ row_ptr,
                                              int* __restrict__ col_src) {
    int base = blockIdx.x * 1024 + threadIdx.x;
    #pragma unroll
    for (int j = 0; j < 4; ++j) {
        int e = base + j * 256;
        if (e < N_EDGES) {
            int d = dst[e];
            if ((uint_t)d >= (uint_t)N_NODES) continue;
            int pos = row_ptr[d] + rank[e];
            int s = src[e];
            if ((uint_t)s >= (uint_t)N_NODES) s = 0;
            if ((uint_t)pos < (uint_t)N_EDGES) col_src[pos] = s;
        }
    }
}

// ---------------- aggregation on bf16 y (dim 64) ----------------
// u[node] = (1+eps)*y[node] + sum_{in edges} y[src] + b1
// One wave per node; 16 lanes cover the 128B bf16 row (uint2 = 4 cols each);
// 4 edges per step (gid = lane>>4), 4 independent streams; unrolled guarded remainder.
__global__ __launch_bounds__(256) void k_aggregate_u(const uint2* __restrict__ y2,
                                                     const int* __restrict__ row_ptr,
                                                     const int* __restrict__ col_src,
                                                     const float* __restrict__ eps, int layer,
                                                     const float* __restrict__ b1,
                                                     float* __restrict__ u) {
    int wid = threadIdx.x >> 6, lane = threadIdx.x & 63;
    int gid = lane >> 4, l4 = lane & 15;
    int node = blockIdx.x * 4 + wid;
    if (node >= N_NODES) return;
    float one_eps = 1.0f + eps[layer];
    int e0 = row_ptr[node], e1 = row_ptr[node + 1];
    if (e0 < 0) e0 = 0;
    if (e1 > N_EDGES) e1 = N_EDGES;
    if (e1 < e0) e1 = e0;
    int len = e1 - e0;
    int main_end = e0 + (len & ~15);

    float4 acc[4];
    #pragma unroll
    for (int j = 0; j < 4; ++j) acc[j] = (float4){0.f, 0.f, 0.f, 0.f};

    for (int eb = e0; eb < main_end; eb += 16) {
        #pragma unroll
        for (int j = 0; j < 4; ++j) {
            int s = col_src[eb + 4 * j + gid];
            if ((uint_t)s >= (uint_t)N_NODES) s = 0;
            uint2 w = y2[(size_t)s * 16 + l4];
            acc[j].x += lo_bf(w.x); acc[j].y += hi_bf(w.x);
            acc[j].z += lo_bf(w.y); acc[j].w += hi_bf(w.y);
        }
    }
    // remainder (<16 edges): 4 independent guarded streams
    #pragma unroll
    for (int j = 0; j < 4; ++j) {
        int ee = main_end + 4 * j + gid;
        if (ee < e1) {
            int s = col_src[ee];
            if ((uint_t)s >= (uint_t)N_NODES) s = 0;
            uint2 w = y2[(size_t)s * 16 + l4];
            acc[j].x += lo_bf(w.x); acc[j].y += hi_bf(w.x);
            acc[j].z += lo_bf(w.y); acc[j].w += hi_bf(w.y);
        }
    }

    float4 t;
    t.x = (acc[0].x + acc[1].x) + (acc[2].x + acc[3].x);
    t.y = (acc[0].y + acc[1].y) + (acc[2].y + acc[3].y);
    t.z = (acc[0].z + acc[1].z) + (acc[2].z + acc[3].z);
    t.w = (acc[0].w + acc[1].w) + (acc[2].w + acc[3].w);
    t.x += __shfl_xor(t.x, 16, 64); t.x += __shfl_xor(t.x, 32, 64);
    t.y += __shfl_xor(t.y, 16, 64); t.y += __shfl_xor(t.y, 32, 64);
    t.z += __shfl_xor(t.z, 16, 64); t.z += __shfl_xor(t.z, 32, 64);
    t.w += __shfl_xor(t.w, 16, 64); t.w += __shfl_xor(t.w, 32, 64);

    if (gid == 0) {
        uint2 ws = y2[(size_t)node * 16 + l4];
        float4 bb = *(const float4*)&b1[4 * l4];
        float4 o;
        o.x = t.x + one_eps * lo_bf(ws.x) + bb.x;
        o.y = t.y + one_eps * hi_bf(ws.x) + bb.y;
        o.z = t.z + one_eps * lo_bf(ws.y) + bb.z;
        o.w = t.w + one_eps * hi_bf(ws.y) + bb.w;
        ((float4*)u)[(size_t)node * 16 + l4] = o;
    }
}

// ---------------- GEMM1: ybf[N x 64](bf16) = A[N x K](f32) @ W[K x 64]  (no bias) ----------------
template <int K>
__global__ __launch_bounds__(256) void k_gemm1(const float* __restrict__ A,
                                               const float* __restrict__ W,
                                               ushort_t* __restrict__ out) {
    constexpr int KP = K + 4;
    constexpr int KQ = K / 4;
    __shared__ float Al[64 * KP];
    __shared__ float Wl[K * 64];
    int tid = threadIdx.x;
    int base = blockIdx.x * 64;

    for (int i = tid; i < K * 16; i += 256)
        ((float4*)Wl)[i] = ((const float4*)W)[i];

    if (base + 64 <= N_NODES) {
        const float4* Ag = (const float4*)(A + (size_t)base * K);
        for (int i = tid; i < 16 * K; i += 256) {
            int row = i / KQ, kk = (i % KQ) * 4;
            float4 v = Ag[i];
            *(float4*)&Al[row * KP + kk] = v;
        }
    } else {
        for (int i = tid; i < 16 * K; i += 256) {
            int row = i / KQ, kk = (i % KQ) * 4;
            int grow = base + row; if (grow >= N_NODES) grow = N_NODES - 1;
            float4 v = ((const float4*)(A + (size_t)grow * K))[i % KQ];
            *(float4*)&Al[row * KP + kk] = v;
        }
    }
    __syncthreads();

    int ct = (tid & 15) * 4;
    int rb = (tid >> 4) * 4;
    float4 acc0 = {0.f, 0.f, 0.f, 0.f}, acc1 = acc0, acc2 = acc0, acc3 = acc0;
    const float* A0 = &Al[(rb + 0) * KP];
    const float* A1 = &Al[(rb + 1) * KP];
    const float* A2 = &Al[(rb + 2) * KP];
    const float* A3 = &Al[(rb + 3) * KP];
    #pragma unroll 4
    for (int k = 0; k < K; ++k) {
        float4 w = *(const float4*)&Wl[k * 64 + ct];
        float a0 = A0[k], a1 = A1[k], a2 = A2[k], a3 = A3[k];
        acc0.x = fmaf(a0, w.x, acc0.x); acc0.y = fmaf(a0, w.y, acc0.y);
        acc0.z = fmaf(a0, w.z, acc0.z); acc0.w = fmaf(a0, w.w, acc0.w);
        acc1.x = fmaf(a1, w.x, acc1.x); acc1.y = fmaf(a1, w.y, acc1.y);
        acc1.z = fmaf(a1, w.z, acc1.z); acc1.w = fmaf(a1, w.w, acc1.w);
        acc2.x = fmaf(a2, w.x, acc2.x); acc2.y = fmaf(a2, w.y, acc2.y);
        acc2.z = fmaf(a2, w.z, acc2.z); acc2.w = fmaf(a2, w.w, acc2.w);
        acc3.x = fmaf(a3, w.x, acc3.x); acc3.y = fmaf(a3, w.y, acc3.y);
        acc3.z = fmaf(a3, w.z, acc3.z); acc3.w = fmaf(a3, w.w, acc3.w);
    }

    float4 accs[4] = {acc0, acc1, acc2, acc3};
    #pragma unroll
    for (int r = 0; r < 4; ++r) {
        int row = base + rb + r;
        if (row < N_NODES) {
            ushort4 o;
            o.x = f2bf(accs[r].x); o.y = f2bf(accs[r].y);
            o.z = f2bf(accs[r].z); o.w = f2bf(accs[r].w);
            *(ushort4*)&out[(size_t)row * 64 + ct] = o;
        }
    }
}

// ---------------- GEMM2: h = relu( relu(bn(u)) @ W2 + b2 ) ----------------
// BN sc/sh computed in-kernel from raw column sums (finalize fused), applied at staging.
__global__ __launch_bounds__(256) void k_gemm_bn(const float* __restrict__ U,
                                                 const float* __restrict__ W,
                                                 const float* __restrict__ sums,
                                                 const float* __restrict__ g,
                                                 const float* __restrict__ be,
                                                 const float* __restrict__ b2,
                                                 float* __restrict__ out) {
    constexpr int K = 64, KP = 68, KQ = 16;
    __shared__ float Al[64 * KP];
    __shared__ float Wl[K * 64];
    __shared__ __align__(16) float Sc[64];
    __shared__ __align__(16) float Sh[64];
    int tid = threadIdx.x;
    int base = blockIdx.x * 64;

    if (tid < 64) {
        const float inv_n = 1.0f / N_NODES;
        float mean = sums[tid] * inv_n;
        float var = sums[64 + tid] * inv_n - mean * mean;
        if (var < 0.f) var = 0.f;
        float inv = rsqrtf(var + 1e-5f);
        float sc = inv * g[tid];
        Sc[tid] = sc;
        Sh[tid] = be[tid] - mean * sc;
    }

    for (int i = tid; i < K * 16; i += 256)
        ((float4*)Wl)[i] = ((const float4*)W)[i];
    __syncthreads();

    {
        bool full = (base + 64 <= N_NODES);
        for (int i = tid; i < 16 * K; i += 256) {
            int row = i / KQ, kq = i % KQ, kk = kq * 4;
            int grow = base + row;
            if (!full && grow >= N_NODES) grow = N_NODES - 1;
            float4 v = ((const float4*)(U + (size_t)grow * K))[kq];
            float4 sc = *(const float4*)&Sc[kk];
            float4 sh = *(const float4*)&Sh[kk];
            v.x = fmaxf(fmaf(v.x, sc.x, sh.x), 0.f);
            v.y = fmaxf(fmaf(v.y, sc.y, sh.y), 0.f);
            v.z = fmaxf(fmaf(v.z, sc.z, sh.z), 0.f);
            v.w = fmaxf(fmaf(v.w, sc.w, sh.w), 0.f);
            *(float4*)&Al[row * KP + kk] = v;
        }
    }
    __syncthreads();

    int ct = (tid & 15) * 4;
    int rb = (tid >> 4) * 4;
    float4 acc0 = {0.f, 0.f, 0.f, 0.f}, acc1 = acc0, acc2 = acc0, acc3 = acc0;
    const float* A0 = &Al[(rb + 0) * KP];
    const float* A1 = &Al[(rb + 1) * KP];
    const float* A2 = &Al[(rb + 2) * KP];
    const float* A3 = &Al[(rb + 3) * KP];
    #pragma unroll 4
    for (int k = 0; k < K; ++k) {
        float4 w = *(const float4*)&Wl[k * 64 + ct];
        float a0 = A0[k], a1 = A1[k], a2 = A2[k], a3 = A3[k];
        acc0.x = fmaf(a0, w.x, acc0.x); acc0.y = fmaf(a0, w.y, acc0.y);
        acc0.z = fmaf(a0, w.z, acc0.z); acc0.w = fmaf(a0, w.w, acc0.w);
        acc1.x = fmaf(a1, w.x, acc1.x); acc1.y = fmaf(a1, w.y, acc1.y);
        acc1.z = fmaf(a1, w.z, acc1.z); acc1.w = fmaf(a1, w.w, acc1.w);
        acc2.x = fmaf(a2, w.x, acc2.x); acc2.y = fmaf(a2, w.y, acc2.y);
        acc2.z = fmaf(a2, w.z, acc2.z); acc2.w = fmaf(a2, w.w, acc2.w);
        acc3.x = fmaf(a3, w.x, acc3.x); acc3.y = fmaf(a3, w.y, acc3.y);
        acc3.z = fmaf(a3, w.z, acc3.z); acc3.w = fmaf(a3, w.w, acc3.w);
    }

    float4 bb = *(const float4*)&b2[ct];
    float4 accs[4] = {acc0, acc1, acc2, acc3};
    #pragma unroll
    for (int r = 0; r < 4; ++r) {
        int row = base + rb + r;
        if (row < N_NODES) {
            float4 o;
            o.x = fmaxf(accs[r].x + bb.x, 0.f);
            o.y = fmaxf(accs[r].y + bb.y, 0.f);
            o.z = fmaxf(accs[r].z + bb.z, 0.f);
            o.w = fmaxf(accs[r].w + bb.w, 0.f);
            *(float4*)&out[(size_t)row * 64 + ct] = o;
        }
    }
}

// ---------------- column stats over u [N_NODES x 64] ----------------
__global__ __launch_bounds__(256) void k_stats(const float* __restrict__ u, float* __restrict__ sums) {
    __shared__ float s1[256], s2[256];
    int tid = threadIdx.x;
    float a = 0.f, b = 0.f;
    for (size_t i = (size_t)blockIdx.x * 256 + tid; i < (size_t)N_NODES * 64; i += (size_t)gridDim.x * 256) {
        float v = u[i];
        a += v;
        b += v * v;
    }
    s1[tid] = a; s2[tid] = b;
    __syncthreads();
    if (tid < 128) { s1[tid] += s1[tid + 128]; s2[tid] += s2[tid + 128]; }
    __syncthreads();
    if (tid < 64) {
        atomicAdd(&sums[tid], s1[tid] + s1[tid + 64]);
        atomicAdd(&sums[64 + tid], s2[tid] + s2[tid + 64]);
    }
}

// ---------------- per-layer pooling (batch is sorted); 4 waves split the node range ----------------
__global__ __launch_bounds__(256) void k_pool1(const int* __restrict__ batch,
                                               const float* __restrict__ h,
                                               float* __restrict__ pooled, int layer) {
    __shared__ float red[256];
    int g = blockIdx.x, tid = threadIdx.x;
    int c = tid & 63, wv = tid >> 6;
    int lo = 0, hi = N_NODES;
    while (lo < hi) { int mid = (lo + hi) >> 1; if (batch[mid] < g) lo = mid + 1; else hi = mid; }
    int s = lo;
    lo = s; hi = N_NODES;
    while (lo < hi) { int mid = (lo + hi) >> 1; if (batch[mid] < g + 1) lo = mid + 1; else hi = mid; }
    int e = lo;
    int len = e - s;
    int chunk = (len + 3) >> 2;
    int ns = s + wv * chunk;
    int ne = ns + chunk; if (ne > e) ne = e;
    float a0 = 0.f, a1 = 0.f, a2 = 0.f, a3 = 0.f, a4 = 0.f, a5 = 0.f, a6 = 0.f, a7 = 0.f;
    int n = ns;
    for (; n + 8 <= ne; n += 8) {
        a0 += h[(size_t)(n + 0) * 64 + c];
        a1 += h[(size_t)(n + 1) * 64 + c];
        a2 += h[(size_t)(n + 2) * 64 + c];
        a3 += h[(size_t)(n + 3) * 64 + c];
        a4 += h[(size_t)(n + 4) * 64 + c];
        a5 += h[(size_t)(n + 5) * 64 + c];
        a6 += h[(size_t)(n + 6) * 64 + c];
        a7 += h[(size_t)(n + 7) * 64 + c];
    }
    for (; n < ne; ++n) a0 += h[(size_t)n * 64 + c];
    red[tid] = ((a0 + a1) + (a2 + a3)) + ((a4 + a5) + (a6 + a7));
    __syncthreads();
    if (wv == 0)
        pooled[g * 256 + layer * 64 + c] = (red[c] + red[64 + c]) + (red[128 + c] + red[192 + c]);
}

// ---------------- head ----------------
__global__ __launch_bounds__(64) void k_head1(const float* __restrict__ pooled,
                                              const float* __restrict__ W, const float* __restrict__ b,
                                              float* __restrict__ t1) {
    int g = blockIdx.x, lane = threadIdx.x;
    const float* p = pooled + g * 256;
    float acc = b[lane];
    for (int k = 0; k < 256; ++k) acc += p[k] * W[k * 64 + lane];
    t1[g * 64 + lane] = acc;
}

__global__ __launch_bounds__(64) void k_head2(const float* __restrict__ t1,
                                              const float* __restrict__ g_, const float* __restrict__ b_,
                                              float* __restrict__ scsh) {
    int c = threadIdx.x;
    float s = 0.f, q = 0.f;
    for (int r = 0; r < N_GRAPHS; ++r) {
        float v = t1[r * 64 + c];
        s += v; q += v * v;
    }
    float mean = s * (1.0f / N_GRAPHS);
    float var = q * (1.0f / N_GRAPHS) - mean * mean;
    if (var < 0.f) var = 0.f;
    float inv = rsqrtf(var + 1e-5f);
    float sc = inv * g_[c];
    scsh[c] = sc;
    scsh[64 + c] = b_[c] - mean * sc;
}

__global__ __launch_bounds__(64) void k_head3(const float* __restrict__ t1, const float* __restrict__ scsh,
                                              const float* __restrict__ W2, const float* __restrict__ b2,
                                              float* __restrict__ out) {
    __shared__ float v[64];
    __shared__ float o[16];
    int g = blockIdx.x, lane = threadIdx.x;
    float x = t1[g * 64 + lane] * scsh[lane] + scsh[64 + lane];
    v[lane] = fmaxf(x, 0.f);
    __syncthreads();
    if (lane < N_CLASSES) {
        float acc = b2[lane];
        for (int k = 0; k < 64; ++k) acc += v[k] * W2[k * N_CLASSES + lane];
        o[lane] = acc;
    }
    __syncthreads();
    if (lane < N_CLASSES) {
        float m = -1e30f;
        for (int k = 0; k < N_CLASSES; ++k) m = fmaxf(m, o[k]);
        float ssum = 0.f;
        for (int k = 0; k < N_CLASSES; ++k) ssum += expf(o[k] - m);
        out[g * N_CLASSES + lane] = o[lane] - m - logf(ssum);
    }
}

// ---------------- launch ----------------
extern "C" void kernel_launch(void* const* d_in, const int* in_sizes, int n_in,
                              void* d_out, int out_size, void* d_ws, size_t ws_size,
                              hipStream_t stream) {
    const float* x      = (const float*)d_in[0];
    const int*   ei     = (const int*)d_in[1];
    const int*   srcArr = ei;
    const int*   dstArr = ei + N_EDGES;
    const int*   batch  = (const int*)d_in[2];
    const float* eps    = (const float*)d_in[3];
    const float* W1_0   = (const float*)d_in[4];
    const float* b1_0   = (const float*)d_in[5];
    const float* g_0    = (const float*)d_in[6];
    const float* be_0   = (const float*)d_in[7];
    const float* W2_0   = (const float*)d_in[8];
    const float* b2_0   = (const float*)d_in[9];
    const float* W1_r   = (const float*)d_in[10];
    const float* b1_r   = (const float*)d_in[11];
    const float* g_r    = (const float*)d_in[12];
    const float* be_r   = (const float*)d_in[13];
    const float* W2_r   = (const float*)d_in[14];
    const float* b2_r   = (const float*)d_in[15];
    const float* lin1W  = (const float*)d_in[16];
    const float* lin1b  = (const float*)d_in[17];
    const float* bn_g   = (const float*)d_in[18];
    const float* bn_b   = (const float*)d_in[19];
    const float* lin2W  = (const float*)d_in[20];
    const float* lin2b  = (const float*)d_in[21];

    char* ws = (char*)d_ws;
    auto alloc = [&](size_t bytes) {
        char* p = ws;
        ws += (bytes + 255) & ~(size_t)255;
        return p;
    };
    int*      deg     = (int*)alloc((size_t)N_NODES * 4);
    int*      row_ptr = (int*)alloc(((size_t)N_NODES + 1) * 4);
    int*      rank    = (int*)alloc((size_t)N_EDGES * 4);
    int*      bsum    = (int*)alloc((size_t)N_TILES * 4);
    int*      boff    = (int*)alloc(((size_t)N_TILES + 1) * 4);
    int*      col_src = (int*)alloc((size_t)N_EDGES * 4);
    ushort_t* ybf     = (ushort_t*)alloc((size_t)N_NODES * 64 * 2);
    float*    u       = (float*)alloc((size_t)N_NODES * 64 * 4);
    float*    hA      = (float*)alloc((size_t)N_NODES * 64 * 4);
    float*    hB      = (float*)alloc((size_t)N_NODES * 64 * 4);
    float*    statsA  = (float*)alloc(NLAYERS * 128 * 4);
    float*    pooled  = (float*)alloc((size_t)N_GRAPHS * 256 * 4);
    float*    t1      = (float*)alloc((size_t)N_GRAPHS * 64 * 4);
    float*    hscsh   = (float*)alloc(128 * 4);

    hipMemsetAsync(deg, 0, (size_t)N_NODES * 4, stream);
    hipMemsetAsync(statsA, 0, NLAYERS * 128 * 4, stream);

    const int e4_grid = (N_EDGES + 1023) / 1024;
    k_degree_rank<<<e4_grid, 256, 0, stream>>>(dstArr, deg, rank);
    k_tilesum<<<N_TILES, 256, 0, stream>>>(deg, bsum);
    k_tilescan<<<1, 512, 0, stream>>>(bsum, boff);
    k_tileapply<<<N_TILES, 256, 0, stream>>>(deg, boff, row_ptr);
    k_fill<<<e4_grid, 256, 0, stream>>>(srcArr, dstArr, rank, row_ptr, col_src);

    const int agg_grid  = N_NODES / 4;              // 25000, exact
    const int gemm_grid = (N_NODES + 63) / 64;      // 1563

    const float* hin = x;
    float* hping[2] = {hA, hB};
    for (int l = 0; l < NLAYERS; ++l) {
        const float *W1, *b1, *gg, *be, *W2, *b2;
        if (l == 0) { W1 = W1_0; b1 = b1_0; gg = g_0; be = be_0; W2 = W2_0; b2 = b2_0; }
        else {
            W1 = W1_r + (size_t)(l - 1) * 64 * 64;
            b1 = b1_r + (size_t)(l - 1) * 64;
            gg = g_r  + (size_t)(l - 1) * 64;
            be = be_r + (size_t)(l - 1) * 64;
            W2 = W2_r + (size_t)(l - 1) * 64 * 64;
            b2 = b2_r + (size_t)(l - 1) * 64;
        }
        float* hout = hping[l & 1];
        // y = bf16(h @ W1)   (bias folded into aggregate)
        if (l == 0) k_gemm1<128><<<gemm_grid, 256, 0, stream>>>(hin, W1, ybf);
        else        k_gemm1<64><<<gemm_grid, 256, 0, stream>>>(hin, W1, ybf);
        // u = (1+eps)*y + sum y[src] + b1
        k_aggregate_u<<<agg_grid, 256, 0, stream>>>((const uint2*)ybf, row_ptr, col_src, eps, l, b1, u);
        k_stats<<<1024, 256, 0, stream>>>(u, statsA + l * 128);
        // h = relu( relu(bn(u)) @ W2 + b2 )   (BN finalize fused in preamble)
        k_gemm_bn<<<gemm_grid, 256, 0, stream>>>(u, W2, statsA + l * 128, gg, be, b2, hout);
        k_pool1<<<N_GRAPHS, 256, 0, stream>>>(batch, hout, pooled, l);
        hin = hout;
    }

    k_head1<<<N_GRAPHS, 64, 0, stream>>>(pooled, lin1W, lin1b, t1);
    k_head2<<<1, 64, 0, stream>>>(t1, bn_g, bn_b, hscsh);
    k_head3<<<N_GRAPHS, 64, 0, stream>>>(t1, hscsh, lin2W, lin2b, (float*)d_out);
}

// Round 10
// 728.978 us; speedup vs baseline: 1.9393x; 1.0872x over previous
//
#include <hip/hip_runtime.h>

#define N_NODES 100000
#define N_EDGES 1600000
#define F_IN 128
#define HID 64
#define NLAYERS 4
#define N_GRAPHS 512
#define N_CLASSES 10
#define N_TILES ((N_NODES + 255) / 256)   // 391

typedef unsigned int uint_t;
typedef unsigned short ushort_t;

__device__ __forceinline__ float lo_bf(uint_t w) { return __uint_as_float(w << 16); }
__device__ __forceinline__ float hi_bf(uint_t w) { return __uint_as_float(w & 0xffff0000u); }
__device__ __forceinline__ ushort_t f2bf(float f) {
    uint_t u = __float_as_uint(f);
    u += 0x7fffu + ((u >> 16) & 1u);   // round-to-nearest-even
    return (ushort_t)(u >> 16);
}

// ---------------- CSR build ----------------
__global__ __launch_bounds__(256) void k_degree_rank(const int* __restrict__ dst,
                                                     int* __restrict__ deg,
                                                     int* __restrict__ rank) {
    int base = blockIdx.x * 1024 + threadIdx.x;
    #pragma unroll
    for (int j = 0; j < 4; ++j) {
        int e = base + j * 256;
        if (e < N_EDGES) {
            int d = dst[e];
            int r = 0;
            if ((uint_t)d < (uint_t)N_NODES) r = atomicAdd(&deg[d], 1);
            rank[e] = r;
        }
    }
}

__global__ __launch_bounds__(256) void k_tilesum(const int* __restrict__ deg, int* __restrict__ bsum) {
    __shared__ int sh[256];
    int tid = threadIdx.x;
    int i = blockIdx.x * 256 + tid;
    sh[tid] = (i < N_NODES) ? deg[i] : 0;
    __syncthreads();
    for (int off = 128; off > 0; off >>= 1) {
        if (tid < off) sh[tid] += sh[tid + off];
        __syncthreads();
    }
    if (tid == 0) bsum[blockIdx.x] = sh[0];
}

__global__ __launch_bounds__(512) void k_tilescan(const int* __restrict__ bsum, int* __restrict__ boff) {
    __shared__ int sh[512];
    int tid = threadIdx.x;
    sh[tid] = (tid < N_TILES) ? bsum[tid] : 0;
    __syncthreads();
    for (int off = 1; off < 512; off <<= 1) {
        int t = (tid >= off) ? sh[tid - off] : 0;
        __syncthreads();
        sh[tid] += t;
        __syncthreads();
    }
    if (tid < N_TILES) boff[tid + 1] = sh[tid];
    if (tid == 0) boff[0] = 0;
}

__global__ __launch_bounds__(256) void k_tileapply(const int* __restrict__ deg, const int* __restrict__ boff,
                                                   int* __restrict__ row_ptr) {
    __shared__ int sh[256];
    int tid = threadIdx.x, b = blockIdx.x;
    int i = b * 256 + tid;
    sh[tid] = (i < N_NODES) ? deg[i] : 0;
    __syncthreads();
    for (int off = 1; off < 256; off <<= 1) {
        int t = (tid >= off) ? sh[tid - off] : 0;
        __syncthreads();
        sh[tid] += t;
        __syncthreads();
    }
    if (i < N_NODES) row_ptr[i + 1] = boff[b] + sh[tid];
    if (i == 0) row_ptr[0] = 0;
}

__global__ __launch_bounds__(256) void k_fill(const int* __restrict__ src, const int* __restrict__ dst,
                                              const int* __restrict__ rank, const int* __restrict__ row_ptr,
                                              int* __restrict__ col_src) {
    int base = blockIdx.x * 1024 + threadIdx.x;
    #pragma unroll
    for (int j = 0; j < 4; ++j) {
        int e = base + j * 256;
        if (e < N_EDGES) {
            int d = dst[e];
            if ((uint_t)d >= (uint_t)N_NODES) continue;
            int pos = row_ptr[d] + rank[e];
            int s = src[e];
            if ((uint_t)s >= (uint_t)N_NODES) s = 0;
            if ((uint_t)pos < (uint_t)N_EDGES) col_src[pos] = s;
        }
    }
}

// ---------------- aggregation on bf16 y (dim 64) ----------------
__global__ __launch_bounds__(256) void k_aggregate_u(const uint2* __restrict__ y2,
                                                     const int* __restrict__ row_ptr,
                                                     const int* __restrict__ col_src,
                                                     const float* __restrict__ eps, int layer,
                                                     const float* __restrict__ b1,
                                                     float* __restrict__ u) {
    int wid = threadIdx.x >> 6, lane = threadIdx.x & 63;
    int gid = lane >> 4, l4 = lane & 15;
    int node = blockIdx.x * 4 + wid;
    if (node >= N_NODES) return;
    float one_eps = 1.0f + eps[layer];
    int e0 = row_ptr[node], e1 = row_ptr[node + 1];
    if (e0 < 0) e0 = 0;
    if (e1 > N_EDGES) e1 = N_EDGES;
    if (e1 < e0) e1 = e0;
    int len = e1 - e0;
    int main_end = e0 + (len & ~15);

    float4 acc[4];
    #pragma unroll
    for (int j = 0; j < 4; ++j) acc[j] = (float4){0.f, 0.f, 0.f, 0.f};

    for (int eb = e0; eb < main_end; eb += 16) {
        #pragma unroll
        for (int j = 0; j < 4; ++j) {
            int s = col_src[eb + 4 * j + gid];
            if ((uint_t)s >= (uint_t)N_NODES) s = 0;
            uint2 w = y2[(size_t)s * 16 + l4];
            acc[j].x += lo_bf(w.x); acc[j].y += hi_bf(w.x);
            acc[j].z += lo_bf(w.y); acc[j].w += hi_bf(w.y);
        }
    }
    #pragma unroll
    for (int j = 0; j < 4; ++j) {
        int ee = main_end + 4 * j + gid;
        if (ee < e1) {
            int s = col_src[ee];
            if ((uint_t)s >= (uint_t)N_NODES) s = 0;
            uint2 w = y2[(size_t)s * 16 + l4];
            acc[j].x += lo_bf(w.x); acc[j].y += hi_bf(w.x);
            acc[j].z += lo_bf(w.y); acc[j].w += hi_bf(w.y);
        }
    }

    float4 t;
    t.x = (acc[0].x + acc[1].x) + (acc[2].x + acc[3].x);
    t.y = (acc[0].y + acc[1].y) + (acc[2].y + acc[3].y);
    t.z = (acc[0].z + acc[1].z) + (acc[2].z + acc[3].z);
    t.w = (acc[0].w + acc[1].w) + (acc[2].w + acc[3].w);
    t.x += __shfl_xor(t.x, 16, 64); t.x += __shfl_xor(t.x, 32, 64);
    t.y += __shfl_xor(t.y, 16, 64); t.y += __shfl_xor(t.y, 32, 64);
    t.z += __shfl_xor(t.z, 16, 64); t.z += __shfl_xor(t.z, 32, 64);
    t.w += __shfl_xor(t.w, 16, 64); t.w += __shfl_xor(t.w, 32, 64);

    if (gid == 0) {
        uint2 ws = y2[(size_t)node * 16 + l4];
        float4 bb = *(const float4*)&b1[4 * l4];
        float4 o;
        o.x = t.x + one_eps * lo_bf(ws.x) + bb.x;
        o.y = t.y + one_eps * hi_bf(ws.x) + bb.y;
        o.z = t.z + one_eps * lo_bf(ws.y) + bb.z;
        o.w = t.w + one_eps * hi_bf(ws.y) + bb.w;
        ((float4*)u)[(size_t)node * 16 + l4] = o;
    }
}

// ---------------- GEMM1 (layer 0 only): ybf = bf16(x @ W1_0) ----------------
template <int K>
__global__ __launch_bounds__(256) void k_gemm1(const float* __restrict__ A,
                                               const float* __restrict__ W,
                                               ushort_t* __restrict__ out) {
    constexpr int KP = K + 4;
    constexpr int KQ = K / 4;
    __shared__ float Al[64 * KP];
    __shared__ float Wl[K * 64];
    int tid = threadIdx.x;
    int base = blockIdx.x * 64;

    for (int i = tid; i < K * 16; i += 256)
        ((float4*)Wl)[i] = ((const float4*)W)[i];

    if (base + 64 <= N_NODES) {
        const float4* Ag = (const float4*)(A + (size_t)base * K);
        for (int i = tid; i < 16 * K; i += 256) {
            int row = i / KQ, kk = (i % KQ) * 4;
            float4 v = Ag[i];
            *(float4*)&Al[row * KP + kk] = v;
        }
    } else {
        for (int i = tid; i < 16 * K; i += 256) {
            int row = i / KQ, kk = (i % KQ) * 4;
            int grow = base + row; if (grow >= N_NODES) grow = N_NODES - 1;
            float4 v = ((const float4*)(A + (size_t)grow * K))[i % KQ];
            *(float4*)&Al[row * KP + kk] = v;
        }
    }
    __syncthreads();

    int ct = (tid & 15) * 4;
    int rb = (tid >> 4) * 4;
    float4 acc0 = {0.f, 0.f, 0.f, 0.f}, acc1 = acc0, acc2 = acc0, acc3 = acc0;
    const float* A0 = &Al[(rb + 0) * KP];
    const float* A1 = &Al[(rb + 1) * KP];
    const float* A2 = &Al[(rb + 2) * KP];
    const float* A3 = &Al[(rb + 3) * KP];
    #pragma unroll 4
    for (int k = 0; k < K; ++k) {
        float4 w = *(const float4*)&Wl[k * 64 + ct];
        float a0 = A0[k], a1 = A1[k], a2 = A2[k], a3 = A3[k];
        acc0.x = fmaf(a0, w.x, acc0.x); acc0.y = fmaf(a0, w.y, acc0.y);
        acc0.z = fmaf(a0, w.z, acc0.z); acc0.w = fmaf(a0, w.w, acc0.w);
        acc1.x = fmaf(a1, w.x, acc1.x); acc1.y = fmaf(a1, w.y, acc1.y);
        acc1.z = fmaf(a1, w.z, acc1.z); acc1.w = fmaf(a1, w.w, acc1.w);
        acc2.x = fmaf(a2, w.x, acc2.x); acc2.y = fmaf(a2, w.y, acc2.y);
        acc2.z = fmaf(a2, w.z, acc2.z); acc2.w = fmaf(a2, w.w, acc2.w);
        acc3.x = fmaf(a3, w.x, acc3.x); acc3.y = fmaf(a3, w.y, acc3.y);
        acc3.z = fmaf(a3, w.z, acc3.z); acc3.w = fmaf(a3, w.w, acc3.w);
    }

    float4 accs[4] = {acc0, acc1, acc2, acc3};
    #pragma unroll
    for (int r = 0; r < 4; ++r) {
        int row = base + rb + r;
        if (row < N_NODES) {
            ushort4 o;
            o.x = f2bf(accs[r].x); o.y = f2bf(accs[r].y);
            o.z = f2bf(accs[r].z); o.w = f2bf(accs[r].w);
            *(ushort4*)&out[(size_t)row * 64 + ct] = o;
        }
    }
}

// ---------------- fused layer tail ----------------
// h = relu( relu(bn(u)) @ W2 + b2 )   [h tile kept in LDS, never hits HBM]
// pooled[g, layer] += per-graph sums of h        (sorted batch -> segment atomics)
// if NEXT: ynext = bf16( h @ W1n )
template <bool NEXT>
__global__ __launch_bounds__(256) void k_fused(const float* __restrict__ U,
                                               const float* __restrict__ W2,
                                               const float* __restrict__ sums,
                                               const float* __restrict__ g_,
                                               const float* __restrict__ be,
                                               const float* __restrict__ b2,
                                               const int* __restrict__ batch,
                                               float* __restrict__ pooled, int layer,
                                               const float* __restrict__ W1n,
                                               ushort_t* __restrict__ ynext) {
    constexpr int K = 64, KP = 68, KQ = 16;
    __shared__ float Al[64 * KP];
    __shared__ float Wl[K * 64];
    __shared__ float W1l[NEXT ? K * 64 : 4];
    __shared__ float Pl[256];
    __shared__ __align__(16) float Sc[64];
    __shared__ __align__(16) float Sh[64];
    int tid = threadIdx.x;
    int base = blockIdx.x * 64;

    if (tid < 64) {
        const float inv_n = 1.0f / N_NODES;
        float mean = sums[tid] * inv_n;
        float var = sums[64 + tid] * inv_n - mean * mean;
        if (var < 0.f) var = 0.f;
        float inv = rsqrtf(var + 1e-5f);
        float sc = inv * g_[tid];
        Sc[tid] = sc;
        Sh[tid] = be[tid] - mean * sc;
    }
    for (int i = tid; i < K * 16; i += 256)
        ((float4*)Wl)[i] = ((const float4*)W2)[i];
    if (NEXT) {
        for (int i = tid; i < K * 16; i += 256)
            ((float4*)W1l)[i] = ((const float4*)W1n)[i];
    }
    __syncthreads();

    {
        bool full = (base + 64 <= N_NODES);
        for (int i = tid; i < 16 * K; i += 256) {
            int row = i / KQ, kq = i % KQ, kk = kq * 4;
            int grow = base + row;
            if (!full && grow >= N_NODES) grow = N_NODES - 1;
            float4 v = ((const float4*)(U + (size_t)grow * K))[kq];
            float4 sc = *(const float4*)&Sc[kk];
            float4 sh = *(const float4*)&Sh[kk];
            v.x = fmaxf(fmaf(v.x, sc.x, sh.x), 0.f);
            v.y = fmaxf(fmaf(v.y, sc.y, sh.y), 0.f);
            v.z = fmaxf(fmaf(v.z, sc.z, sh.z), 0.f);
            v.w = fmaxf(fmaf(v.w, sc.w, sh.w), 0.f);
            *(float4*)&Al[row * KP + kk] = v;
        }
    }
    __syncthreads();

    int ct = (tid & 15) * 4;
    int rb = (tid >> 4) * 4;
    float4 acc0 = {0.f, 0.f, 0.f, 0.f}, acc1 = acc0, acc2 = acc0, acc3 = acc0;
    {
        const float* A0 = &Al[(rb + 0) * KP];
        const float* A1 = &Al[(rb + 1) * KP];
        const float* A2 = &Al[(rb + 2) * KP];
        const float* A3 = &Al[(rb + 3) * KP];
        #pragma unroll 4
        for (int k = 0; k < K; ++k) {
            float4 w = *(const float4*)&Wl[k * 64 + ct];
            float a0 = A0[k], a1 = A1[k], a2 = A2[k], a3 = A3[k];
            acc0.x = fmaf(a0, w.x, acc0.x); acc0.y = fmaf(a0, w.y, acc0.y);
            acc0.z = fmaf(a0, w.z, acc0.z); acc0.w = fmaf(a0, w.w, acc0.w);
            acc1.x = fmaf(a1, w.x, acc1.x); acc1.y = fmaf(a1, w.y, acc1.y);
            acc1.z = fmaf(a1, w.z, acc1.z); acc1.w = fmaf(a1, w.w, acc1.w);
            acc2.x = fmaf(a2, w.x, acc2.x); acc2.y = fmaf(a2, w.y, acc2.y);
            acc2.z = fmaf(a2, w.z, acc2.z); acc2.w = fmaf(a2, w.w, acc2.w);
            acc3.x = fmaf(a3, w.x, acc3.x); acc3.y = fmaf(a3, w.y, acc3.y);
            acc3.z = fmaf(a3, w.z, acc3.z); acc3.w = fmaf(a3, w.w, acc3.w);
        }
    }
    __syncthreads();   // done reading Al (u); reuse it for h

    {
        float4 bb = *(const float4*)&b2[ct];
        float4 accs[4] = {acc0, acc1, acc2, acc3};
        #pragma unroll
        for (int r = 0; r < 4; ++r) {
            float4 o;
            o.x = fmaxf(accs[r].x + bb.x, 0.f);
            o.y = fmaxf(accs[r].y + bb.y, 0.f);
            o.z = fmaxf(accs[r].z + bb.z, 0.f);
            o.w = fmaxf(accs[r].w + bb.w, 0.f);
            *(float4*)&Al[(rb + r) * KP + ct] = o;
        }
    }
    __syncthreads();   // h tile ready in Al

    // ---- pooling over graph segments (batch sorted) ----
    {
        int lastEx = base + 64; if (lastEx > N_NODES) lastEx = N_NODES;
        int gstart = batch[base];
        int gend = batch[lastEx - 1];
        if (gstart < 0) gstart = 0;
        if (gend > N_GRAPHS - 1) gend = N_GRAPHS - 1;
        int col = tid & 63, q = tid >> 6;
        int rs = base;
        for (int g = gstart; g <= gend; ++g) {
            int lo = rs, hi = lastEx;
            while (lo < hi) { int mid = (lo + hi) >> 1; if (batch[mid] <= g) lo = mid + 1; else hi = mid; }
            int re = lo;
            float s = 0.f;
            for (int r = rs + q; r < re; r += 4) s += Al[(r - base) * KP + col];
            Pl[tid] = s;
            __syncthreads();
            if (tid < 64) {
                float tot = (Pl[col] + Pl[64 + col]) + (Pl[128 + col] + Pl[192 + col]);
                atomicAdd(&pooled[g * 256 + layer * 64 + col], tot);
            }
            __syncthreads();
            rs = re;
        }
    }

    // ---- second GEMM: ynext = bf16( h @ W1n ) ----
    if (NEXT) {
        float4 y0 = {0.f, 0.f, 0.f, 0.f}, y1 = y0, y2_ = y0, y3 = y0;
        const float* A0 = &Al[(rb + 0) * KP];
        const float* A1 = &Al[(rb + 1) * KP];
        const float* A2 = &Al[(rb + 2) * KP];
        const float* A3 = &Al[(rb + 3) * KP];
        #pragma unroll 4
        for (int k = 0; k < K; ++k) {
            float4 w = *(const float4*)&W1l[k * 64 + ct];
            float a0 = A0[k], a1 = A1[k], a2 = A2[k], a3 = A3[k];
            y0.x = fmaf(a0, w.x, y0.x); y0.y = fmaf(a0, w.y, y0.y);
            y0.z = fmaf(a0, w.z, y0.z); y0.w = fmaf(a0, w.w, y0.w);
            y1.x = fmaf(a1, w.x, y1.x); y1.y = fmaf(a1, w.y, y1.y);
            y1.z = fmaf(a1, w.z, y1.z); y1.w = fmaf(a1, w.w, y1.w);
            y2_.x = fmaf(a2, w.x, y2_.x); y2_.y = fmaf(a2, w.y, y2_.y);
            y2_.z = fmaf(a2, w.z, y2_.z); y2_.w = fmaf(a2, w.w, y2_.w);
            y3.x = fmaf(a3, w.x, y3.x); y3.y = fmaf(a3, w.y, y3.y);
            y3.z = fmaf(a3, w.z, y3.z); y3.w = fmaf(a3, w.w, y3.w);
        }
        float4 ys[4] = {y0, y1, y2_, y3};
        #pragma unroll
        for (int r = 0; r < 4; ++r) {
            int row = base + rb + r;
            if (row < N_NODES) {
                ushort4 o;
                o.x = f2bf(ys[r].x); o.y = f2bf(ys[r].y);
                o.z = f2bf(ys[r].z); o.w = f2bf(ys[r].w);
                *(ushort4*)&ynext[(size_t)row * 64 + ct] = o;
            }
        }
    }
}

// ---------------- column stats over u [N_NODES x 64] ----------------
__global__ __launch_bounds__(256) void k_stats(const float* __restrict__ u, float* __restrict__ sums) {
    __shared__ float s1[256], s2[256];
    int tid = threadIdx.x;
    float a = 0.f, b = 0.f;
    for (size_t i = (size_t)blockIdx.x * 256 + tid; i < (size_t)N_NODES * 64; i += (size_t)gridDim.x * 256) {
        float v = u[i];
        a += v;
        b += v * v;
    }
    s1[tid] = a; s2[tid] = b;
    __syncthreads();
    if (tid < 128) { s1[tid] += s1[tid + 128]; s2[tid] += s2[tid + 128]; }
    __syncthreads();
    if (tid < 64) {
        atomicAdd(&sums[tid], s1[tid] + s1[tid + 64]);
        atomicAdd(&sums[64 + tid], s2[tid] + s2[tid + 64]);
    }
}

// ---------------- head ----------------
__global__ __launch_bounds__(64) void k_head1(const float* __restrict__ pooled,
                                              const float* __restrict__ W, const float* __restrict__ b,
                                              float* __restrict__ t1) {
    int g = blockIdx.x, lane = threadIdx.x;
    const float* p = pooled + g * 256;
    float acc = b[lane];
    for (int k = 0; k < 256; ++k) acc += p[k] * W[k * 64 + lane];
    t1[g * 64 + lane] = acc;
}

__global__ __launch_bounds__(64) void k_head2(const float* __restrict__ t1,
                                              const float* __restrict__ g_, const float* __restrict__ b_,
                                              float* __restrict__ scsh) {
    int c = threadIdx.x;
    float s = 0.f, q = 0.f;
    for (int r = 0; r < N_GRAPHS; ++r) {
        float v = t1[r * 64 + c];
        s += v; q += v * v;
    }
    float mean = s * (1.0f / N_GRAPHS);
    float var = q * (1.0f / N_GRAPHS) - mean * mean;
    if (var < 0.f) var = 0.f;
    float inv = rsqrtf(var + 1e-5f);
    float sc = inv * g_[c];
    scsh[c] = sc;
    scsh[64 + c] = b_[c] - mean * sc;
}

__global__ __launch_bounds__(64) void k_head3(const float* __restrict__ t1, const float* __restrict__ scsh,
                                              const float* __restrict__ W2, const float* __restrict__ b2,
                                              float* __restrict__ out) {
    __shared__ float v[64];
    __shared__ float o[16];
    int g = blockIdx.x, lane = threadIdx.x;
    float x = t1[g * 64 + lane] * scsh[lane] + scsh[64 + lane];
    v[lane] = fmaxf(x, 0.f);
    __syncthreads();
    if (lane < N_CLASSES) {
        float acc = b2[lane];
        for (int k = 0; k < 64; ++k) acc += v[k] * W2[k * N_CLASSES + lane];
        o[lane] = acc;
    }
    __syncthreads();
    if (lane < N_CLASSES) {
        float m = -1e30f;
        for (int k = 0; k < N_CLASSES; ++k) m = fmaxf(m, o[k]);
        float ssum = 0.f;
        for (int k = 0; k < N_CLASSES; ++k) ssum += expf(o[k] - m);
        out[g * N_CLASSES + lane] = o[lane] - m - logf(ssum);
    }
}

// ---------------- launch ----------------
extern "C" void kernel_launch(void* const* d_in, const int* in_sizes, int n_in,
                              void* d_out, int out_size, void* d_ws, size_t ws_size,
                              hipStream_t stream) {
    const float* x      = (const float*)d_in[0];
    const int*   ei     = (const int*)d_in[1];
    const int*   srcArr = ei;
    const int*   dstArr = ei + N_EDGES;
    const int*   batch  = (const int*)d_in[2];
    const float* eps    = (const float*)d_in[3];
    const float* W1_0   = (const float*)d_in[4];
    const float* b1_0   = (const float*)d_in[5];
    const float* g_0    = (const float*)d_in[6];
    const float* be_0   = (const float*)d_in[7];
    const float* W2_0   = (const float*)d_in[8];
    const float* b2_0   = (const float*)d_in[9];
    const float* W1_r   = (const float*)d_in[10];
    const float* b1_r   = (const float*)d_in[11];
    const float* g_r    = (const float*)d_in[12];
    const float* be_r   = (const float*)d_in[13];
    const float* W2_r   = (const float*)d_in[14];
    const float* b2_r   = (const float*)d_in[15];
    const float* lin1W  = (const float*)d_in[16];
    const float* lin1b  = (const float*)d_in[17];
    const float* bn_g   = (const float*)d_in[18];
    const float* bn_b   = (const float*)d_in[19];
    const float* lin2W  = (const float*)d_in[20];
    const float* lin2b  = (const float*)d_in[21];

    char* ws = (char*)d_ws;
    auto alloc = [&](size_t bytes) {
        char* p = ws;
        ws += (bytes + 255) & ~(size_t)255;
        return p;
    };
    int*      deg     = (int*)alloc((size_t)N_NODES * 4);
    int*      row_ptr = (int*)alloc(((size_t)N_NODES + 1) * 4);
    int*      rank    = (int*)alloc((size_t)N_EDGES * 4);
    int*      bsum    = (int*)alloc((size_t)N_TILES * 4);
    int*      boff    = (int*)alloc(((size_t)N_TILES + 1) * 4);
    int*      col_src = (int*)alloc((size_t)N_EDGES * 4);
    ushort_t* ybf     = (ushort_t*)alloc((size_t)N_NODES * 64 * 2);
    float*    u       = (float*)alloc((size_t)N_NODES * 64 * 4);
    float*    statsA  = (float*)alloc(NLAYERS * 128 * 4);
    float*    pooled  = (float*)alloc((size_t)N_GRAPHS * 256 * 4);
    float*    t1      = (float*)alloc((size_t)N_GRAPHS * 64 * 4);
    float*    hscsh   = (float*)alloc(128 * 4);

    hipMemsetAsync(deg, 0, (size_t)N_NODES * 4, stream);
    hipMemsetAsync(statsA, 0, NLAYERS * 128 * 4, stream);
    hipMemsetAsync(pooled, 0, (size_t)N_GRAPHS * 256 * 4, stream);

    const int e4_grid = (N_EDGES + 1023) / 1024;
    k_degree_rank<<<e4_grid, 256, 0, stream>>>(dstArr, deg, rank);
    k_tilesum<<<N_TILES, 256, 0, stream>>>(deg, bsum);
    k_tilescan<<<1, 512, 0, stream>>>(bsum, boff);
    k_tileapply<<<N_TILES, 256, 0, stream>>>(deg, boff, row_ptr);
    k_fill<<<e4_grid, 256, 0, stream>>>(srcArr, dstArr, rank, row_ptr, col_src);

    const int agg_grid  = N_NODES / 4;              // 25000, exact
    const int gemm_grid = (N_NODES + 63) / 64;      // 1563

    // layer 0 front GEMM: y0 = bf16(x @ W1_0)
    k_gemm1<128><<<gemm_grid, 256, 0, stream>>>(x, W1_0, ybf);

    for (int l = 0; l < NLAYERS; ++l) {
        const float *b1, *gg, *be, *W2, *b2;
        if (l == 0) { b1 = b1_0; gg = g_0; be = be_0; W2 = W2_0; b2 = b2_0; }
        else {
            b1 = b1_r + (size_t)(l - 1) * 64;
            gg = g_r  + (size_t)(l - 1) * 64;
            be = be_r + (size_t)(l - 1) * 64;
            W2 = W2_r + (size_t)(l - 1) * 64 * 64;
            b2 = b2_r + (size_t)(l - 1) * 64;
        }
        // u = (1+eps)*y + sum y[src] + b1
        k_aggregate_u<<<agg_grid, 256, 0, stream>>>((const uint2*)ybf, row_ptr, col_src, eps, l, b1, u);
        k_stats<<<1024, 256, 0, stream>>>(u, statsA + l * 128);
        // fused: BN+ReLU -> @W2+b2+ReLU -> pooling (+ next-layer GEMM1)
        if (l < NLAYERS - 1) {
            const float* W1n = W1_r + (size_t)l * 64 * 64;   // layer l+1 weights
            k_fused<true><<<gemm_grid, 256, 0, stream>>>(u, W2, statsA + l * 128, gg, be, b2,
                                                         batch, pooled, l, W1n, ybf);
        } else {
            k_fused<false><<<gemm_grid, 256, 0, stream>>>(u, W2, statsA + l * 128, gg, be, b2,
                                                          batch, pooled, l, nullptr, nullptr);
        }
    }

    k_head1<<<N_GRAPHS, 64, 0, stream>>>(pooled, lin1W, lin1b, t1);
    k_head2<<<1, 64, 0, stream>>>(t1, bn_g, bn_b, hscsh);
    k_head3<<<N_GRAPHS, 64, 0, stream>>>(t1, hscsh, lin2W, lin2b, (float*)d_out);
}

// Round 11
// 694.003 us; speedup vs baseline: 2.0370x; 1.0504x over previous
//
#include <hip/hip_runtime.h>

#define N_NODES 100000
#define N_EDGES 1600000
#define F_IN 128
#define HID 64
#define NLAYERS 4
#define N_GRAPHS 512
#define N_CLASSES 10
#define N_TILES ((N_NODES + 255) / 256)   // 391

typedef unsigned int uint_t;
typedef unsigned short ushort_t;

__device__ __forceinline__ float lo_bf(uint_t w) { return __uint_as_float(w << 16); }
__device__ __forceinline__ float hi_bf(uint_t w) { return __uint_as_float(w & 0xffff0000u); }
__device__ __forceinline__ ushort_t f2bf(float f) {
    uint_t u = __float_as_uint(f);
    u += 0x7fffu + ((u >> 16) & 1u);   // round-to-nearest-even
    return (ushort_t)(u >> 16);
}

// ---------------- workspace zeroing (deg + statsA + pooled) in one dispatch ----------------
__global__ __launch_bounds__(256) void k_zero(int* __restrict__ deg,
                                              float* __restrict__ statsA,
                                              float* __restrict__ pooled) {
    int i = blockIdx.x * 256 + threadIdx.x;
    if (i < N_NODES) deg[i] = 0;
    if (i < NLAYERS * 128) statsA[i] = 0.f;
    if (i < N_GRAPHS * 256) pooled[i] = 0.f;
}

// ---------------- CSR build ----------------
__global__ __launch_bounds__(256) void k_degree_rank(const int* __restrict__ dst,
                                                     int* __restrict__ deg,
                                                     int* __restrict__ rank) {
    int base = blockIdx.x * 1024 + threadIdx.x;
    #pragma unroll
    for (int j = 0; j < 4; ++j) {
        int e = base + j * 256;
        if (e < N_EDGES) {
            int d = dst[e];
            int r = 0;
            if ((uint_t)d < (uint_t)N_NODES) r = atomicAdd(&deg[d], 1);
            rank[e] = r;
        }
    }
}

__global__ __launch_bounds__(256) void k_tilesum(const int* __restrict__ deg, int* __restrict__ bsum) {
    __shared__ int sh[256];
    int tid = threadIdx.x;
    int i = blockIdx.x * 256 + tid;
    sh[tid] = (i < N_NODES) ? deg[i] : 0;
    __syncthreads();
    for (int off = 128; off > 0; off >>= 1) {
        if (tid < off) sh[tid] += sh[tid + off];
        __syncthreads();
    }
    if (tid == 0) bsum[blockIdx.x] = sh[0];
}

__global__ __launch_bounds__(512) void k_tilescan(const int* __restrict__ bsum, int* __restrict__ boff) {
    __shared__ int sh[512];
    int tid = threadIdx.x;
    sh[tid] = (tid < N_TILES) ? bsum[tid] : 0;
    __syncthreads();
    for (int off = 1; off < 512; off <<= 1) {
        int t = (tid >= off) ? sh[tid - off] : 0;
        __syncthreads();
        sh[tid] += t;
        __syncthreads();
    }
    if (tid < N_TILES) boff[tid + 1] = sh[tid];
    if (tid == 0) boff[0] = 0;
}

__global__ __launch_bounds__(256) void k_tileapply(const int* __restrict__ deg, const int* __restrict__ boff,
                                                   int* __restrict__ row_ptr) {
    __shared__ int sh[256];
    int tid = threadIdx.x, b = blockIdx.x;
    int i = b * 256 + tid;
    sh[tid] = (i < N_NODES) ? deg[i] : 0;
    __syncthreads();
    for (int off = 1; off < 256; off <<= 1) {
        int t = (tid >= off) ? sh[tid - off] : 0;
        __syncthreads();
        sh[tid] += t;
        __syncthreads();
    }
    if (i < N_NODES) row_ptr[i + 1] = boff[b] + sh[tid];
    if (i == 0) row_ptr[0] = 0;
}

__global__ __launch_bounds__(256) void k_fill(const int* __restrict__ src, const int* __restrict__ dst,
                                              const int* __restrict__ rank, const int* __restrict__ row_ptr,
                                              int* __restrict__ col_src) {
    int base = blockIdx.x * 1024 + threadIdx.x;
    #pragma unroll
    for (int j = 0; j < 4; ++j) {
        int e = base + j * 256;
        if (e < N_EDGES) {
            int d = dst[e];
            if ((uint_t)d >= (uint_t)N_NODES) continue;
            int pos = row_ptr[d] + rank[e];
            uint_t s = (uint_t)src[e];
            if (s >= (uint_t)N_NODES) s = 0;
            if ((uint_t)pos < (uint_t)N_EDGES) col_src[pos] = (int)s;
        }
    }
}

// ---------------- aggregation on bf16 y (dim 64) ----------------
__global__ __launch_bounds__(256) void k_aggregate_u(const uint2* __restrict__ y2,
                                                     const int* __restrict__ row_ptr,
                                                     const int* __restrict__ col_src,
                                                     const float* __restrict__ eps, int layer,
                                                     const float* __restrict__ b1,
                                                     float* __restrict__ u) {
    int wid = threadIdx.x >> 6, lane = threadIdx.x & 63;
    int gid = lane >> 4, l4 = lane & 15;
    int node = blockIdx.x * 4 + wid;
    if (node >= N_NODES) return;
    float one_eps = 1.0f + eps[layer];
    int e0 = row_ptr[node], e1 = row_ptr[node + 1];
    if (e0 < 0) e0 = 0;
    if (e1 > N_EDGES) e1 = N_EDGES;
    if (e1 < e0) e1 = e0;
    int len = e1 - e0;
    int main_end = e0 + (len & ~15);

    float4 acc[4];
    #pragma unroll
    for (int j = 0; j < 4; ++j) acc[j] = (float4){0.f, 0.f, 0.f, 0.f};

    for (int eb = e0; eb < main_end; eb += 16) {
        #pragma unroll
        for (int j = 0; j < 4; ++j) {
            uint_t s = min((uint_t)col_src[eb + 4 * j + gid], (uint_t)(N_NODES - 1));
            uint2 w = y2[(size_t)s * 16 + l4];
            acc[j].x += lo_bf(w.x); acc[j].y += hi_bf(w.x);
            acc[j].z += lo_bf(w.y); acc[j].w += hi_bf(w.y);
        }
    }
    #pragma unroll
    for (int j = 0; j < 4; ++j) {
        int ee = main_end + 4 * j + gid;
        if (ee < e1) {
            uint_t s = min((uint_t)col_src[ee], (uint_t)(N_NODES - 1));
            uint2 w = y2[(size_t)s * 16 + l4];
            acc[j].x += lo_bf(w.x); acc[j].y += hi_bf(w.x);
            acc[j].z += lo_bf(w.y); acc[j].w += hi_bf(w.y);
        }
    }

    float4 t;
    t.x = (acc[0].x + acc[1].x) + (acc[2].x + acc[3].x);
    t.y = (acc[0].y + acc[1].y) + (acc[2].y + acc[3].y);
    t.z = (acc[0].z + acc[1].z) + (acc[2].z + acc[3].z);
    t.w = (acc[0].w + acc[1].w) + (acc[2].w + acc[3].w);
    t.x += __shfl_xor(t.x, 16, 64); t.x += __shfl_xor(t.x, 32, 64);
    t.y += __shfl_xor(t.y, 16, 64); t.y += __shfl_xor(t.y, 32, 64);
    t.z += __shfl_xor(t.z, 16, 64); t.z += __shfl_xor(t.z, 32, 64);
    t.w += __shfl_xor(t.w, 16, 64); t.w += __shfl_xor(t.w, 32, 64);

    if (gid == 0) {
        uint2 ws = y2[(size_t)node * 16 + l4];
        float4 bb = *(const float4*)&b1[4 * l4];
        float4 o;
        o.x = t.x + one_eps * lo_bf(ws.x) + bb.x;
        o.y = t.y + one_eps * hi_bf(ws.x) + bb.y;
        o.z = t.z + one_eps * lo_bf(ws.y) + bb.z;
        o.w = t.w + one_eps * hi_bf(ws.y) + bb.w;
        ((float4*)u)[(size_t)node * 16 + l4] = o;
    }
}

// ---------------- GEMM1 (layer 0 only): ybf = bf16(x @ W1_0) ----------------
template <int K>
__global__ __launch_bounds__(256) void k_gemm1(const float* __restrict__ A,
                                               const float* __restrict__ W,
                                               ushort_t* __restrict__ out) {
    constexpr int KP = K + 4;
    constexpr int KQ = K / 4;
    __shared__ float Al[64 * KP];
    __shared__ float Wl[K * 64];
    int tid = threadIdx.x;
    int base = blockIdx.x * 64;

    for (int i = tid; i < K * 16; i += 256)
        ((float4*)Wl)[i] = ((const float4*)W)[i];

    if (base + 64 <= N_NODES) {
        const float4* Ag = (const float4*)(A + (size_t)base * K);
        for (int i = tid; i < 16 * K; i += 256) {
            int row = i / KQ, kk = (i % KQ) * 4;
            float4 v = Ag[i];
            *(float4*)&Al[row * KP + kk] = v;
        }
    } else {
        for (int i = tid; i < 16 * K; i += 256) {
            int row = i / KQ, kk = (i % KQ) * 4;
            int grow = base + row; if (grow >= N_NODES) grow = N_NODES - 1;
            float4 v = ((const float4*)(A + (size_t)grow * K))[i % KQ];
            *(float4*)&Al[row * KP + kk] = v;
        }
    }
    __syncthreads();

    int ct = (tid & 15) * 4;
    int rb = (tid >> 4) * 4;
    float4 acc0 = {0.f, 0.f, 0.f, 0.f}, acc1 = acc0, acc2 = acc0, acc3 = acc0;
    const float* A0 = &Al[(rb + 0) * KP];
    const float* A1 = &Al[(rb + 1) * KP];
    const float* A2 = &Al[(rb + 2) * KP];
    const float* A3 = &Al[(rb + 3) * KP];
    #pragma unroll 4
    for (int k = 0; k < K; ++k) {
        float4 w = *(const float4*)&Wl[k * 64 + ct];
        float a0 = A0[k], a1 = A1[k], a2 = A2[k], a3 = A3[k];
        acc0.x = fmaf(a0, w.x, acc0.x); acc0.y = fmaf(a0, w.y, acc0.y);
        acc0.z = fmaf(a0, w.z, acc0.z); acc0.w = fmaf(a0, w.w, acc0.w);
        acc1.x = fmaf(a1, w.x, acc1.x); acc1.y = fmaf(a1, w.y, acc1.y);
        acc1.z = fmaf(a1, w.z, acc1.z); acc1.w = fmaf(a1, w.w, acc1.w);
        acc2.x = fmaf(a2, w.x, acc2.x); acc2.y = fmaf(a2, w.y, acc2.y);
        acc2.z = fmaf(a2, w.z, acc2.z); acc2.w = fmaf(a2, w.w, acc2.w);
        acc3.x = fmaf(a3, w.x, acc3.x); acc3.y = fmaf(a3, w.y, acc3.y);
        acc3.z = fmaf(a3, w.z, acc3.z); acc3.w = fmaf(a3, w.w, acc3.w);
    }

    float4 accs[4] = {acc0, acc1, acc2, acc3};
    #pragma unroll
    for (int r = 0; r < 4; ++r) {
        int row = base + rb + r;
        if (row < N_NODES) {
            ushort4 o;
            o.x = f2bf(accs[r].x); o.y = f2bf(accs[r].y);
            o.z = f2bf(accs[r].z); o.w = f2bf(accs[r].w);
            *(ushort4*)&out[(size_t)row * 64 + ct] = o;
        }
    }
}

// ---------------- fused layer tail ----------------
template <bool NEXT>
__global__ __launch_bounds__(256) void k_fused(const float* __restrict__ U,
                                               const float* __restrict__ W2,
                                               const float* __restrict__ sums,
                                               const float* __restrict__ g_,
                                               const float* __restrict__ be,
                                               const float* __restrict__ b2,
                                               const int* __restrict__ batch,
                                               float* __restrict__ pooled, int layer,
                                               const float* __restrict__ W1n,
                                               ushort_t* __restrict__ ynext) {
    constexpr int K = 64, KP = 68, KQ = 16;
    __shared__ float Al[64 * KP];
    __shared__ float Wl[K * 64];
    __shared__ float W1l[NEXT ? K * 64 : 4];
    __shared__ float Pl[256];
    __shared__ __align__(16) float Sc[64];
    __shared__ __align__(16) float Sh[64];
    int tid = threadIdx.x;
    int base = blockIdx.x * 64;

    if (tid < 64) {
        const float inv_n = 1.0f / N_NODES;
        float mean = sums[tid] * inv_n;
        float var = sums[64 + tid] * inv_n - mean * mean;
        if (var < 0.f) var = 0.f;
        float inv = rsqrtf(var + 1e-5f);
        float sc = inv * g_[tid];
        Sc[tid] = sc;
        Sh[tid] = be[tid] - mean * sc;
    }
    for (int i = tid; i < K * 16; i += 256)
        ((float4*)Wl)[i] = ((const float4*)W2)[i];
    if (NEXT) {
        for (int i = tid; i < K * 16; i += 256)
            ((float4*)W1l)[i] = ((const float4*)W1n)[i];
    }
    __syncthreads();

    {
        bool full = (base + 64 <= N_NODES);
        for (int i = tid; i < 16 * K; i += 256) {
            int row = i / KQ, kq = i % KQ, kk = kq * 4;
            int grow = base + row;
            if (!full && grow >= N_NODES) grow = N_NODES - 1;
            float4 v = ((const float4*)(U + (size_t)grow * K))[kq];
            float4 sc = *(const float4*)&Sc[kk];
            float4 sh = *(const float4*)&Sh[kk];
            v.x = fmaxf(fmaf(v.x, sc.x, sh.x), 0.f);
            v.y = fmaxf(fmaf(v.y, sc.y, sh.y), 0.f);
            v.z = fmaxf(fmaf(v.z, sc.z, sh.z), 0.f);
            v.w = fmaxf(fmaf(v.w, sc.w, sh.w), 0.f);
            *(float4*)&Al[row * KP + kk] = v;
        }
    }
    __syncthreads();

    int ct = (tid & 15) * 4;
    int rb = (tid >> 4) * 4;
    float4 acc0 = {0.f, 0.f, 0.f, 0.f}, acc1 = acc0, acc2 = acc0, acc3 = acc0;
    {
        const float* A0 = &Al[(rb + 0) * KP];
        const float* A1 = &Al[(rb + 1) * KP];
        const float* A2 = &Al[(rb + 2) * KP];
        const float* A3 = &Al[(rb + 3) * KP];
        #pragma unroll 4
        for (int k = 0; k < K; ++k) {
            float4 w = *(const float4*)&Wl[k * 64 + ct];
            float a0 = A0[k], a1 = A1[k], a2 = A2[k], a3 = A3[k];
            acc0.x = fmaf(a0, w.x, acc0.x); acc0.y = fmaf(a0, w.y, acc0.y);
            acc0.z = fmaf(a0, w.z, acc0.z); acc0.w = fmaf(a0, w.w, acc0.w);
            acc1.x = fmaf(a1, w.x, acc1.x); acc1.y = fmaf(a1, w.y, acc1.y);
            acc1.z = fmaf(a1, w.z, acc1.z); acc1.w = fmaf(a1, w.w, acc1.w);
            acc2.x = fmaf(a2, w.x, acc2.x); acc2.y = fmaf(a2, w.y, acc2.y);
            acc2.z = fmaf(a2, w.z, acc2.z); acc2.w = fmaf(a2, w.w, acc2.w);
            acc3.x = fmaf(a3, w.x, acc3.x); acc3.y = fmaf(a3, w.y, acc3.y);
            acc3.z = fmaf(a3, w.z, acc3.z); acc3.w = fmaf(a3, w.w, acc3.w);
        }
    }
    __syncthreads();   // done reading Al (u); reuse it for h

    {
        float4 bb = *(const float4*)&b2[ct];
        float4 accs[4] = {acc0, acc1, acc2, acc3};
        #pragma unroll
        for (int r = 0; r < 4; ++r) {
            float4 o;
            o.x = fmaxf(accs[r].x + bb.x, 0.f);
            o.y = fmaxf(accs[r].y + bb.y, 0.f);
            o.z = fmaxf(accs[r].z + bb.z, 0.f);
            o.w = fmaxf(accs[r].w + bb.w, 0.f);
            *(float4*)&Al[(rb + r) * KP + ct] = o;
        }
    }
    __syncthreads();   // h tile ready in Al

    // ---- pooling over graph segments (batch sorted) ----
    {
        int lastEx = base + 64; if (lastEx > N_NODES) lastEx = N_NODES;
        int gstart = batch[base];
        int gend = batch[lastEx - 1];
        if (gstart < 0) gstart = 0;
        if (gend > N_GRAPHS - 1) gend = N_GRAPHS - 1;
        int col = tid & 63, q = tid >> 6;
        int rs = base;
        for (int g = gstart; g <= gend; ++g) {
            int lo = rs, hi = lastEx;
            while (lo < hi) { int mid = (lo + hi) >> 1; if (batch[mid] <= g) lo = mid + 1; else hi = mid; }
            int re = lo;
            float s = 0.f;
            for (int r = rs + q; r < re; r += 4) s += Al[(r - base) * KP + col];
            Pl[tid] = s;
            __syncthreads();
            if (tid < 64) {
                float tot = (Pl[col] + Pl[64 + col]) + (Pl[128 + col] + Pl[192 + col]);
                atomicAdd(&pooled[g * 256 + layer * 64 + col], tot);
            }
            __syncthreads();
            rs = re;
        }
    }

    // ---- second GEMM: ynext = bf16( h @ W1n ) ----
    if (NEXT) {
        float4 y0 = {0.f, 0.f, 0.f, 0.f}, y1 = y0, y2_ = y0, y3 = y0;
        const float* A0 = &Al[(rb + 0) * KP];
        const float* A1 = &Al[(rb + 1) * KP];
        const float* A2 = &Al[(rb + 2) * KP];
        const float* A3 = &Al[(rb + 3) * KP];
        #pragma unroll 4
        for (int k = 0; k < K; ++k) {
            float4 w = *(const float4*)&W1l[k * 64 + ct];
            float a0 = A0[k], a1 = A1[k], a2 = A2[k], a3 = A3[k];
            y0.x = fmaf(a0, w.x, y0.x); y0.y = fmaf(a0, w.y, y0.y);
            y0.z = fmaf(a0, w.z, y0.z); y0.w = fmaf(a0, w.w, y0.w);
            y1.x = fmaf(a1, w.x, y1.x); y1.y = fmaf(a1, w.y, y1.y);
            y1.z = fmaf(a1, w.z, y1.z); y1.w = fmaf(a1, w.w, y1.w);
            y2_.x = fmaf(a2, w.x, y2_.x); y2_.y = fmaf(a2, w.y, y2_.y);
            y2_.z = fmaf(a2, w.z, y2_.z); y2_.w = fmaf(a2, w.w, y2_.w);
            y3.x = fmaf(a3, w.x, y3.x); y3.y = fmaf(a3, w.y, y3.y);
            y3.z = fmaf(a3, w.z, y3.z); y3.w = fmaf(a3, w.w, y3.w);
        }
        float4 ys[4] = {y0, y1, y2_, y3};
        #pragma unroll
        for (int r = 0; r < 4; ++r) {
            int row = base + rb + r;
            if (row < N_NODES) {
                ushort4 o;
                o.x = f2bf(ys[r].x); o.y = f2bf(ys[r].y);
                o.z = f2bf(ys[r].z); o.w = f2bf(ys[r].w);
                *(ushort4*)&ynext[(size_t)row * 64 + ct] = o;
            }
        }
    }
}

// ---------------- column stats over u [N_NODES x 64] ----------------
__global__ __launch_bounds__(256) void k_stats(const float* __restrict__ u, float* __restrict__ sums) {
    __shared__ float s1[256], s2[256];
    int tid = threadIdx.x;
    float a = 0.f, b = 0.f;
    for (size_t i = (size_t)blockIdx.x * 256 + tid; i < (size_t)N_NODES * 64; i += (size_t)gridDim.x * 256) {
        float v = u[i];
        a += v;
        b += v * v;
    }
    s1[tid] = a; s2[tid] = b;
    __syncthreads();
    if (tid < 128) { s1[tid] += s1[tid + 128]; s2[tid] += s2[tid + 128]; }
    __syncthreads();
    if (tid < 64) {
        atomicAdd(&sums[tid], s1[tid] + s1[tid + 64]);
        atomicAdd(&sums[64 + tid], s2[tid] + s2[tid + 64]);
    }
}

// ---------------- head ----------------
__global__ __launch_bounds__(64) void k_head1(const float* __restrict__ pooled,
                                              const float* __restrict__ W, const float* __restrict__ b,
                                              float* __restrict__ t1) {
    int g = blockIdx.x, lane = threadIdx.x;
    const float* p = pooled + g * 256;
    float acc = b[lane];
    for (int k = 0; k < 256; ++k) acc += p[k] * W[k * 64 + lane];
    t1[g * 64 + lane] = acc;
}

// head2 folded in: each block recomputes BN stats from t1 (L2-hot, 128KB)
__global__ __launch_bounds__(64) void k_head3(const float* __restrict__ t1,
                                              const float* __restrict__ g_, const float* __restrict__ b_,
                                              const float* __restrict__ W2, const float* __restrict__ b2,
                                              float* __restrict__ out) {
    __shared__ float v[64];
    __shared__ float o[16];
    int g = blockIdx.x, lane = threadIdx.x;
    float s = 0.f, q = 0.f;
    for (int r = 0; r < N_GRAPHS; ++r) {
        float vv = t1[r * 64 + lane];
        s += vv; q += vv * vv;
    }
    float mean = s * (1.0f / N_GRAPHS);
    float var = q * (1.0f / N_GRAPHS) - mean * mean;
    if (var < 0.f) var = 0.f;
    float inv = rsqrtf(var + 1e-5f);
    float sc = inv * g_[lane];
    float sh = b_[lane] - mean * sc;
    float x = t1[g * 64 + lane] * sc + sh;
    v[lane] = fmaxf(x, 0.f);
    __syncthreads();
    if (lane < N_CLASSES) {
        float acc = b2[lane];
        for (int k = 0; k < 64; ++k) acc += v[k] * W2[k * N_CLASSES + lane];
        o[lane] = acc;
    }
    __syncthreads();
    if (lane < N_CLASSES) {
        float m = -1e30f;
        for (int k = 0; k < N_CLASSES; ++k) m = fmaxf(m, o[k]);
        float ssum = 0.f;
        for (int k = 0; k < N_CLASSES; ++k) ssum += expf(o[k] - m);
        out[g * N_CLASSES + lane] = o[lane] - m - logf(ssum);
    }
}

// ---------------- launch ----------------
extern "C" void kernel_launch(void* const* d_in, const int* in_sizes, int n_in,
                              void* d_out, int out_size, void* d_ws, size_t ws_size,
                              hipStream_t stream) {
    const float* x      = (const float*)d_in[0];
    const int*   ei     = (const int*)d_in[1];
    const int*   srcArr = ei;
    const int*   dstArr = ei + N_EDGES;
    const int*   batch  = (const int*)d_in[2];
    const float* eps    = (const float*)d_in[3];
    const float* W1_0   = (const float*)d_in[4];
    const float* b1_0   = (const float*)d_in[5];
    const float* g_0    = (const float*)d_in[6];
    const float* be_0   = (const float*)d_in[7];
    const float* W2_0   = (const float*)d_in[8];
    const float* b2_0   = (const float*)d_in[9];
    const float* W1_r   = (const float*)d_in[10];
    const float* b1_r   = (const float*)d_in[11];
    const float* g_r    = (const float*)d_in[12];
    const float* be_r   = (const float*)d_in[13];
    const float* W2_r   = (const float*)d_in[14];
    const float* b2_r   = (const float*)d_in[15];
    const float* lin1W  = (const float*)d_in[16];
    const float* lin1b  = (const float*)d_in[17];
    const float* bn_g   = (const float*)d_in[18];
    const float* bn_b   = (const float*)d_in[19];
    const float* lin2W  = (const float*)d_in[20];
    const float* lin2b  = (const float*)d_in[21];

    char* ws = (char*)d_ws;
    auto alloc = [&](size_t bytes) {
        char* p = ws;
        ws += (bytes + 255) & ~(size_t)255;
        return p;
    };
    int*      deg     = (int*)alloc((size_t)N_NODES * 4);
    int*      row_ptr = (int*)alloc(((size_t)N_NODES + 1) * 4);
    int*      rank    = (int*)alloc((size_t)N_EDGES * 4);
    int*      bsum    = (int*)alloc((size_t)N_TILES * 4);
    int*      boff    = (int*)alloc(((size_t)N_TILES + 1) * 4);
    int*      col_src = (int*)alloc((size_t)N_EDGES * 4);
    ushort_t* ybf     = (ushort_t*)alloc((size_t)N_NODES * 64 * 2);
    float*    u       = (float*)alloc((size_t)N_NODES * 64 * 4);
    float*    statsA  = (float*)alloc(NLAYERS * 128 * 4);
    float*    pooled  = (float*)alloc((size_t)N_GRAPHS * 256 * 4);
    float*    t1      = (float*)alloc((size_t)N_GRAPHS * 64 * 4);

    const int e4_grid = (N_EDGES + 1023) / 1024;
    k_zero<<<(N_GRAPHS * 256 + 255) / 256, 256, 0, stream>>>(deg, statsA, pooled);
    k_degree_rank<<<e4_grid, 256, 0, stream>>>(dstArr, deg, rank);
    k_tilesum<<<N_TILES, 256, 0, stream>>>(deg, bsum);
    k_tilescan<<<1, 512, 0, stream>>>(bsum, boff);
    k_tileapply<<<N_TILES, 256, 0, stream>>>(deg, boff, row_ptr);
    k_fill<<<e4_grid, 256, 0, stream>>>(srcArr, dstArr, rank, row_ptr, col_src);

    const int agg_grid  = N_NODES / 4;              // 25000, exact
    const int gemm_grid = (N_NODES + 63) / 64;      // 1563

    // layer 0 front GEMM: y0 = bf16(x @ W1_0)
    k_gemm1<128><<<gemm_grid, 256, 0, stream>>>(x, W1_0, ybf);

    for (int l = 0; l < NLAYERS; ++l) {
        const float *b1, *gg, *be, *W2, *b2;
        if (l == 0) { b1 = b1_0; gg = g_0; be = be_0; W2 = W2_0; b2 = b2_0; }
        else {
            b1 = b1_r + (size_t)(l - 1) * 64;
            gg = g_r  + (size_t)(l - 1) * 64;
            be = be_r + (size_t)(l - 1) * 64;
            W2 = W2_r + (size_t)(l - 1) * 64 * 64;
            b2 = b2_r + (size_t)(l - 1) * 64;
        }
        k_aggregate_u<<<agg_grid, 256, 0, stream>>>((const uint2*)ybf, row_ptr, col_src, eps, l, b1, u);
        k_stats<<<512, 256, 0, stream>>>(u, statsA + l * 128);
        if (l < NLAYERS - 1) {
            const float* W1n = W1_r + (size_t)l * 64 * 64;
            k_fused<true><<<gemm_grid, 256, 0, stream>>>(u, W2, statsA + l * 128, gg, be, b2,
                                                         batch, pooled, l, W1n, ybf);
        } else {
            k_fused<false><<<gemm_grid, 256, 0, stream>>>(u, W2, statsA + l * 128, gg, be, b2,
                                                          batch, pooled, l, nullptr, nullptr);
        }
    }

    k_head1<<<N_GRAPHS, 64, 0, stream>>>(pooled, lin1W, lin1b, t1);
    k_head3<<<N_GRAPHS, 64, 0, stream>>>(t1, bn_g, bn_b, lin2W, lin2b, (float*)d_out);
}

// Round 12
// 660.745 us; speedup vs baseline: 2.1395x; 1.0503x over previous
//
#include <hip/hip_runtime.h>

#define N_NODES 100000
#define N_EDGES 1600000
#define F_IN 128
#define HID 64
#define NLAYERS 4
#define N_GRAPHS 512
#define N_CLASSES 10
#define N_TILES ((N_NODES + 255) / 256)   // 391

typedef unsigned int uint_t;
typedef unsigned short ushort_t;

__device__ __forceinline__ float lo_bf(uint_t w) { return __uint_as_float(w << 16); }
__device__ __forceinline__ float hi_bf(uint_t w) { return __uint_as_float(w & 0xffff0000u); }
__device__ __forceinline__ ushort_t f2bf(float f) {
    uint_t u = __float_as_uint(f);
    u += 0x7fffu + ((u >> 16) & 1u);   // round-to-nearest-even
    return (ushort_t)(u >> 16);
}
__device__ __forceinline__ uint_t pack2(float a, float b) {
    return ((uint_t)f2bf(b) << 16) | (uint_t)f2bf(a);
}

// ---------------- workspace zeroing ----------------
__global__ __launch_bounds__(256) void k_zero(int* __restrict__ deg,
                                              float* __restrict__ statsA,
                                              float* __restrict__ pooled) {
    int i = blockIdx.x * 256 + threadIdx.x;
    if (i < N_NODES) deg[i] = 0;
    if (i < NLAYERS * 128) statsA[i] = 0.f;
    if (i < N_GRAPHS * 256) pooled[i] = 0.f;
}

// ---------------- CSR build ----------------
__global__ __launch_bounds__(256) void k_degree_rank(const int* __restrict__ dst,
                                                     int* __restrict__ deg,
                                                     ushort_t* __restrict__ rank) {
    int base = blockIdx.x * 1024 + threadIdx.x;
    #pragma unroll
    for (int j = 0; j < 4; ++j) {
        int e = base + j * 256;
        if (e < N_EDGES) {
            int d = dst[e];
            int r = 0;
            if ((uint_t)d < (uint_t)N_NODES) r = atomicAdd(&deg[d], 1);
            rank[e] = (ushort_t)r;
        }
    }
}

__global__ __launch_bounds__(256) void k_tilesum(const int* __restrict__ deg, int* __restrict__ bsum) {
    __shared__ int sh[256];
    int tid = threadIdx.x;
    int i = blockIdx.x * 256 + tid;
    sh[tid] = (i < N_NODES) ? deg[i] : 0;
    __syncthreads();
    for (int off = 128; off > 0; off >>= 1) {
        if (tid < off) sh[tid] += sh[tid + off];
        __syncthreads();
    }
    if (tid == 0) bsum[blockIdx.x] = sh[0];
}

__global__ __launch_bounds__(512) void k_tilescan(const int* __restrict__ bsum, int* __restrict__ boff) {
    __shared__ int sh[512];
    int tid = threadIdx.x;
    sh[tid] = (tid < N_TILES) ? bsum[tid] : 0;
    __syncthreads();
    for (int off = 1; off < 512; off <<= 1) {
        int t = (tid >= off) ? sh[tid - off] : 0;
        __syncthreads();
        sh[tid] += t;
        __syncthreads();
    }
    if (tid < N_TILES) boff[tid + 1] = sh[tid];
    if (tid == 0) boff[0] = 0;
}

__global__ __launch_bounds__(256) void k_tileapply(const int* __restrict__ deg, const int* __restrict__ boff,
                                                   int* __restrict__ row_ptr) {
    __shared__ int sh[256];
    int tid = threadIdx.x, b = blockIdx.x;
    int i = b * 256 + tid;
    sh[tid] = (i < N_NODES) ? deg[i] : 0;
    __syncthreads();
    for (int off = 1; off < 256; off <<= 1) {
        int t = (tid >= off) ? sh[tid - off] : 0;
        __syncthreads();
        sh[tid] += t;
        __syncthreads();
    }
    if (i < N_NODES) row_ptr[i + 1] = boff[b] + sh[tid];
    if (i == 0) row_ptr[0] = 0;
}

__global__ __launch_bounds__(256) void k_fill(const int* __restrict__ src, const int* __restrict__ dst,
                                              const ushort_t* __restrict__ rank, const int* __restrict__ row_ptr,
                                              int* __restrict__ col_src) {
    int base = blockIdx.x * 1024 + threadIdx.x;
    #pragma unroll
    for (int j = 0; j < 4; ++j) {
        int e = base + j * 256;
        if (e < N_EDGES) {
            int d = dst[e];
            if ((uint_t)d >= (uint_t)N_NODES) continue;
            int pos = row_ptr[d] + (int)rank[e];
            uint_t s = (uint_t)src[e];
            if (s >= (uint_t)N_NODES) s = 0;
            if ((uint_t)pos < (uint_t)N_EDGES) col_src[pos] = (int)s;
        }
    }
}

// ---------------- aggregation on bf16 y (dim 64) -> bf16 u ----------------
__global__ __launch_bounds__(256) void k_aggregate_u(const uint2* __restrict__ y2,
                                                     const int* __restrict__ row_ptr,
                                                     const int* __restrict__ col_src,
                                                     const float* __restrict__ eps, int layer,
                                                     const float* __restrict__ b1,
                                                     uint2* __restrict__ u2) {
    int wid = threadIdx.x >> 6, lane = threadIdx.x & 63;
    int gid = lane >> 4, l4 = lane & 15;
    int node = blockIdx.x * 4 + wid;
    if (node >= N_NODES) return;
    float one_eps = 1.0f + eps[layer];
    int e0 = row_ptr[node], e1 = row_ptr[node + 1];
    if (e0 < 0) e0 = 0;
    if (e1 > N_EDGES) e1 = N_EDGES;
    if (e1 < e0) e1 = e0;
    int len = e1 - e0;
    int main_end = e0 + (len & ~15);

    float4 acc[4];
    #pragma unroll
    for (int j = 0; j < 4; ++j) acc[j] = (float4){0.f, 0.f, 0.f, 0.f};

    for (int eb = e0; eb < main_end; eb += 16) {
        #pragma unroll
        for (int j = 0; j < 4; ++j) {
            uint_t s = min((uint_t)col_src[eb + 4 * j + gid], (uint_t)(N_NODES - 1));
            uint2 w = y2[(size_t)s * 16 + l4];
            acc[j].x += lo_bf(w.x); acc[j].y += hi_bf(w.x);
            acc[j].z += lo_bf(w.y); acc[j].w += hi_bf(w.y);
        }
    }
    #pragma unroll
    for (int j = 0; j < 4; ++j) {
        int ee = main_end + 4 * j + gid;
        if (ee < e1) {
            uint_t s = min((uint_t)col_src[ee], (uint_t)(N_NODES - 1));
            uint2 w = y2[(size_t)s * 16 + l4];
            acc[j].x += lo_bf(w.x); acc[j].y += hi_bf(w.x);
            acc[j].z += lo_bf(w.y); acc[j].w += hi_bf(w.y);
        }
    }

    float4 t;
    t.x = (acc[0].x + acc[1].x) + (acc[2].x + acc[3].x);
    t.y = (acc[0].y + acc[1].y) + (acc[2].y + acc[3].y);
    t.z = (acc[0].z + acc[1].z) + (acc[2].z + acc[3].z);
    t.w = (acc[0].w + acc[1].w) + (acc[2].w + acc[3].w);
    t.x += __shfl_xor(t.x, 16, 64); t.x += __shfl_xor(t.x, 32, 64);
    t.y += __shfl_xor(t.y, 16, 64); t.y += __shfl_xor(t.y, 32, 64);
    t.z += __shfl_xor(t.z, 16, 64); t.z += __shfl_xor(t.z, 32, 64);
    t.w += __shfl_xor(t.w, 16, 64); t.w += __shfl_xor(t.w, 32, 64);

    if (gid == 0) {
        uint2 ws = y2[(size_t)node * 16 + l4];
        float4 bb = *(const float4*)&b1[4 * l4];
        float ox = t.x + one_eps * lo_bf(ws.x) + bb.x;
        float oy = t.y + one_eps * hi_bf(ws.x) + bb.y;
        float oz = t.z + one_eps * lo_bf(ws.y) + bb.z;
        float ow = t.w + one_eps * hi_bf(ws.y) + bb.w;
        uint2 o2;
        o2.x = pack2(ox, oy);
        o2.y = pack2(oz, ow);
        u2[(size_t)node * 16 + l4] = o2;
    }
}

// ---------------- GEMM1 (layer 0 only): ybf = bf16(x @ W1_0) ----------------
template <int K>
__global__ __launch_bounds__(256) void k_gemm1(const float* __restrict__ A,
                                               const float* __restrict__ W,
                                               ushort_t* __restrict__ out) {
    constexpr int KP = K + 4;
    constexpr int KQ = K / 4;
    __shared__ float Al[64 * KP];
    __shared__ float Wl[K * 64];
    int tid = threadIdx.x;
    int base = blockIdx.x * 64;

    for (int i = tid; i < K * 16; i += 256)
        ((float4*)Wl)[i] = ((const float4*)W)[i];

    if (base + 64 <= N_NODES) {
        const float4* Ag = (const float4*)(A + (size_t)base * K);
        for (int i = tid; i < 16 * K; i += 256) {
            int row = i / KQ, kk = (i % KQ) * 4;
            float4 v = Ag[i];
            *(float4*)&Al[row * KP + kk] = v;
        }
    } else {
        for (int i = tid; i < 16 * K; i += 256) {
            int row = i / KQ, kk = (i % KQ) * 4;
            int grow = base + row; if (grow >= N_NODES) grow = N_NODES - 1;
            float4 v = ((const float4*)(A + (size_t)grow * K))[i % KQ];
            *(float4*)&Al[row * KP + kk] = v;
        }
    }
    __syncthreads();

    int ct = (tid & 15) * 4;
    int rb = (tid >> 4) * 4;
    float4 acc0 = {0.f, 0.f, 0.f, 0.f}, acc1 = acc0, acc2 = acc0, acc3 = acc0;
    const float* A0 = &Al[(rb + 0) * KP];
    const float* A1 = &Al[(rb + 1) * KP];
    const float* A2 = &Al[(rb + 2) * KP];
    const float* A3 = &Al[(rb + 3) * KP];
    #pragma unroll 4
    for (int k = 0; k < K; ++k) {
        float4 w = *(const float4*)&Wl[k * 64 + ct];
        float a0 = A0[k], a1 = A1[k], a2 = A2[k], a3 = A3[k];
        acc0.x = fmaf(a0, w.x, acc0.x); acc0.y = fmaf(a0, w.y, acc0.y);
        acc0.z = fmaf(a0, w.z, acc0.z); acc0.w = fmaf(a0, w.w, acc0.w);
        acc1.x = fmaf(a1, w.x, acc1.x); acc1.y = fmaf(a1, w.y, acc1.y);
        acc1.z = fmaf(a1, w.z, acc1.z); acc1.w = fmaf(a1, w.w, acc1.w);
        acc2.x = fmaf(a2, w.x, acc2.x); acc2.y = fmaf(a2, w.y, acc2.y);
        acc2.z = fmaf(a2, w.z, acc2.z); acc2.w = fmaf(a2, w.w, acc2.w);
        acc3.x = fmaf(a3, w.x, acc3.x); acc3.y = fmaf(a3, w.y, acc3.y);
        acc3.z = fmaf(a3, w.z, acc3.z); acc3.w = fmaf(a3, w.w, acc3.w);
    }

    float4 accs[4] = {acc0, acc1, acc2, acc3};
    #pragma unroll
    for (int r = 0; r < 4; ++r) {
        int row = base + rb + r;
        if (row < N_NODES) {
            ushort4 o;
            o.x = f2bf(accs[r].x); o.y = f2bf(accs[r].y);
            o.z = f2bf(accs[r].z); o.w = f2bf(accs[r].w);
            *(ushort4*)&out[(size_t)row * 64 + ct] = o;
        }
    }
}

// ---------------- fused layer tail (bf16 u input) ----------------
template <bool NEXT>
__global__ __launch_bounds__(256) void k_fused(const uint2* __restrict__ U2,
                                               const float* __restrict__ W2,
                                               const float* __restrict__ sums,
                                               const float* __restrict__ g_,
                                               const float* __restrict__ be,
                                               const float* __restrict__ b2,
                                               const int* __restrict__ batch,
                                               float* __restrict__ pooled, int layer,
                                               const float* __restrict__ W1n,
                                               ushort_t* __restrict__ ynext) {
    constexpr int K = 64, KP = 68, KQ = 16;
    __shared__ float Al[64 * KP];
    __shared__ float Wl[K * 64];
    __shared__ float W1l[NEXT ? K * 64 : 4];
    __shared__ float Pl[256];
    __shared__ __align__(16) float Sc[64];
    __shared__ __align__(16) float Sh[64];
    int tid = threadIdx.x;
    int base = blockIdx.x * 64;

    if (tid < 64) {
        const float inv_n = 1.0f / N_NODES;
        float mean = sums[tid] * inv_n;
        float var = sums[64 + tid] * inv_n - mean * mean;
        if (var < 0.f) var = 0.f;
        float inv = rsqrtf(var + 1e-5f);
        float sc = inv * g_[tid];
        Sc[tid] = sc;
        Sh[tid] = be[tid] - mean * sc;
    }
    for (int i = tid; i < K * 16; i += 256)
        ((float4*)Wl)[i] = ((const float4*)W2)[i];
    if (NEXT) {
        for (int i = tid; i < K * 16; i += 256)
            ((float4*)W1l)[i] = ((const float4*)W1n)[i];
    }
    __syncthreads();

    {
        bool full = (base + 64 <= N_NODES);
        for (int i = tid; i < 16 * K; i += 256) {
            int row = i / KQ, kq = i % KQ, kk = kq * 4;
            int grow = base + row;
            if (!full && grow >= N_NODES) grow = N_NODES - 1;
            uint2 w = U2[(size_t)grow * 16 + kq];
            float4 v = {lo_bf(w.x), hi_bf(w.x), lo_bf(w.y), hi_bf(w.y)};
            float4 sc = *(const float4*)&Sc[kk];
            float4 sh = *(const float4*)&Sh[kk];
            v.x = fmaxf(fmaf(v.x, sc.x, sh.x), 0.f);
            v.y = fmaxf(fmaf(v.y, sc.y, sh.y), 0.f);
            v.z = fmaxf(fmaf(v.z, sc.z, sh.z), 0.f);
            v.w = fmaxf(fmaf(v.w, sc.w, sh.w), 0.f);
            *(float4*)&Al[row * KP + kk] = v;
        }
    }
    __syncthreads();

    int ct = (tid & 15) * 4;
    int rb = (tid >> 4) * 4;
    float4 acc0 = {0.f, 0.f, 0.f, 0.f}, acc1 = acc0, acc2 = acc0, acc3 = acc0;
    {
        const float* A0 = &Al[(rb + 0) * KP];
        const float* A1 = &Al[(rb + 1) * KP];
        const float* A2 = &Al[(rb + 2) * KP];
        const float* A3 = &Al[(rb + 3) * KP];
        #pragma unroll 4
        for (int k = 0; k < K; ++k) {
            float4 w = *(const float4*)&Wl[k * 64 + ct];
            float a0 = A0[k], a1 = A1[k], a2 = A2[k], a3 = A3[k];
            acc0.x = fmaf(a0, w.x, acc0.x); acc0.y = fmaf(a0, w.y, acc0.y);
            acc0.z = fmaf(a0, w.z, acc0.z); acc0.w = fmaf(a0, w.w, acc0.w);
            acc1.x = fmaf(a1, w.x, acc1.x); acc1.y = fmaf(a1, w.y, acc1.y);
            acc1.z = fmaf(a1, w.z, acc1.z); acc1.w = fmaf(a1, w.w, acc1.w);
            acc2.x = fmaf(a2, w.x, acc2.x); acc2.y = fmaf(a2, w.y, acc2.y);
            acc2.z = fmaf(a2, w.z, acc2.z); acc2.w = fmaf(a2, w.w, acc2.w);
            acc3.x = fmaf(a3, w.x, acc3.x); acc3.y = fmaf(a3, w.y, acc3.y);
            acc3.z = fmaf(a3, w.z, acc3.z); acc3.w = fmaf(a3, w.w, acc3.w);
        }
    }
    __syncthreads();   // done reading Al (u); reuse it for h

    {
        float4 bb = *(const float4*)&b2[ct];
        float4 accs[4] = {acc0, acc1, acc2, acc3};
        #pragma unroll
        for (int r = 0; r < 4; ++r) {
            float4 o;
            o.x = fmaxf(accs[r].x + bb.x, 0.f);
            o.y = fmaxf(accs[r].y + bb.y, 0.f);
            o.z = fmaxf(accs[r].z + bb.z, 0.f);
            o.w = fmaxf(accs[r].w + bb.w, 0.f);
            *(float4*)&Al[(rb + r) * KP + ct] = o;
        }
    }
    __syncthreads();   // h tile ready in Al

    // ---- pooling over graph segments (batch sorted) ----
    {
        int lastEx = base + 64; if (lastEx > N_NODES) lastEx = N_NODES;
        int gstart = batch[base];
        int gend = batch[lastEx - 1];
        if (gstart < 0) gstart = 0;
        if (gend > N_GRAPHS - 1) gend = N_GRAPHS - 1;
        int col = tid & 63, q = tid >> 6;
        int rs = base;
        for (int g = gstart; g <= gend; ++g) {
            int lo = rs, hi = lastEx;
            while (lo < hi) { int mid = (lo + hi) >> 1; if (batch[mid] <= g) lo = mid + 1; else hi = mid; }
            int re = lo;
            float s = 0.f;
            for (int r = rs + q; r < re; r += 4) s += Al[(r - base) * KP + col];
            Pl[tid] = s;
            __syncthreads();
            if (tid < 64) {
                float tot = (Pl[col] + Pl[64 + col]) + (Pl[128 + col] + Pl[192 + col]);
                atomicAdd(&pooled[g * 256 + layer * 64 + col], tot);
            }
            __syncthreads();
            rs = re;
        }
    }

    // ---- second GEMM: ynext = bf16( h @ W1n ) ----
    if (NEXT) {
        float4 y0 = {0.f, 0.f, 0.f, 0.f}, y1 = y0, y2_ = y0, y3 = y0;
        const float* A0 = &Al[(rb + 0) * KP];
        const float* A1 = &Al[(rb + 1) * KP];
        const float* A2 = &Al[(rb + 2) * KP];
        const float* A3 = &Al[(rb + 3) * KP];
        #pragma unroll 4
        for (int k = 0; k < K; ++k) {
            float4 w = *(const float4*)&W1l[k * 64 + ct];
            float a0 = A0[k], a1 = A1[k], a2 = A2[k], a3 = A3[k];
            y0.x = fmaf(a0, w.x, y0.x); y0.y = fmaf(a0, w.y, y0.y);
            y0.z = fmaf(a0, w.z, y0.z); y0.w = fmaf(a0, w.w, y0.w);
            y1.x = fmaf(a1, w.x, y1.x); y1.y = fmaf(a1, w.y, y1.y);
            y1.z = fmaf(a1, w.z, y1.z); y1.w = fmaf(a1, w.w, y1.w);
            y2_.x = fmaf(a2, w.x, y2_.x); y2_.y = fmaf(a2, w.y, y2_.y);
            y2_.z = fmaf(a2, w.z, y2_.z); y2_.w = fmaf(a2, w.w, y2_.w);
            y3.x = fmaf(a3, w.x, y3.x); y3.y = fmaf(a3, w.y, y3.y);
            y3.z = fmaf(a3, w.z, y3.z); y3.w = fmaf(a3, w.w, y3.w);
        }
        float4 ys[4] = {y0, y1, y2_, y3};
        #pragma unroll
        for (int r = 0; r < 4; ++r) {
            int row = base + rb + r;
            if (row < N_NODES) {
                ushort4 o;
                o.x = f2bf(ys[r].x); o.y = f2bf(ys[r].y);
                o.z = f2bf(ys[r].z); o.w = f2bf(ys[r].w);
                *(ushort4*)&ynext[(size_t)row * 64 + ct] = o;
            }
        }
    }
}

// ---------------- column stats over bf16 u [N_NODES x 64] ----------------
__global__ __launch_bounds__(256) void k_stats(const uint2* __restrict__ u2, float* __restrict__ sums) {
    __shared__ float sh[256 * 8];
    int tid = threadIdx.x;
    float a[4] = {0.f, 0.f, 0.f, 0.f}, b[4] = {0.f, 0.f, 0.f, 0.f};
    for (size_t i = (size_t)blockIdx.x * 256 + tid; i < (size_t)N_NODES * 16; i += (size_t)gridDim.x * 256) {
        uint2 w = u2[i];
        float v0 = lo_bf(w.x), v1 = hi_bf(w.x), v2 = lo_bf(w.y), v3 = hi_bf(w.y);
        a[0] += v0; b[0] += v0 * v0;
        a[1] += v1; b[1] += v1 * v1;
        a[2] += v2; b[2] += v2 * v2;
        a[3] += v3; b[3] += v3 * v3;
    }
    // thread tid covers column quad q = tid & 15 (grid stride multiple of 16)
    #pragma unroll
    for (int j = 0; j < 4; ++j) { sh[tid * 8 + j] = a[j]; sh[tid * 8 + 4 + j] = b[j]; }
    __syncthreads();
    if (tid < 64) {
        int quad = tid >> 2, o = tid & 3;
        float s = 0.f, ss = 0.f;
        for (int g = 0; g < 16; ++g) {
            int t = g * 16 + quad;
            s  += sh[t * 8 + o];
            ss += sh[t * 8 + 4 + o];
        }
        atomicAdd(&sums[tid], s);
        atomicAdd(&sums[64 + tid], ss);
    }
}

// ---------------- head ----------------
__global__ __launch_bounds__(64) void k_head1(const float* __restrict__ pooled,
                                              const float* __restrict__ W, const float* __restrict__ b,
                                              float* __restrict__ t1) {
    __shared__ __align__(16) float pl[256];
    int g = blockIdx.x, lane = threadIdx.x;
    ((float4*)pl)[lane] = ((const float4*)(pooled + g * 256))[lane];
    __syncthreads();
    float acc = b[lane];
    for (int k = 0; k < 256; ++k) acc += pl[k] * W[k * 64 + lane];
    t1[g * 64 + lane] = acc;
}

// head2 folded in: each block recomputes BN stats from t1 (L2-hot, 128KB)
__global__ __launch_bounds__(64) void k_head3(const float* __restrict__ t1,
                                              const float* __restrict__ g_, const float* __restrict__ b_,
                                              const float* __restrict__ W2, const float* __restrict__ b2,
                                              float* __restrict__ out) {
    __shared__ float v[64];
    __shared__ float o[16];
    int g = blockIdx.x, lane = threadIdx.x;
    float s = 0.f, q = 0.f;
    for (int r = 0; r < N_GRAPHS; ++r) {
        float vv = t1[r * 64 + lane];
        s += vv; q += vv * vv;
    }
    float mean = s * (1.0f / N_GRAPHS);
    float var = q * (1.0f / N_GRAPHS) - mean * mean;
    if (var < 0.f) var = 0.f;
    float inv = rsqrtf(var + 1e-5f);
    float sc = inv * g_[lane];
    float sh = b_[lane] - mean * sc;
    float x = t1[g * 64 + lane] * sc + sh;
    v[lane] = fmaxf(x, 0.f);
    __syncthreads();
    if (lane < N_CLASSES) {
        float acc = b2[lane];
        for (int k = 0; k < 64; ++k) acc += v[k] * W2[k * N_CLASSES + lane];
        o[lane] = acc;
    }
    __syncthreads();
    if (lane < N_CLASSES) {
        float m = -1e30f;
        for (int k = 0; k < N_CLASSES; ++k) m = fmaxf(m, o[k]);
        float ssum = 0.f;
        for (int k = 0; k < N_CLASSES; ++k) ssum += expf(o[k] - m);
        out[g * N_CLASSES + lane] = o[lane] - m - logf(ssum);
    }
}

// ---------------- launch ----------------
extern "C" void kernel_launch(void* const* d_in, const int* in_sizes, int n_in,
                              void* d_out, int out_size, void* d_ws, size_t ws_size,
                              hipStream_t stream) {
    const float* x      = (const float*)d_in[0];
    const int*   ei     = (const int*)d_in[1];
    const int*   srcArr = ei;
    const int*   dstArr = ei + N_EDGES;
    const int*   batch  = (const int*)d_in[2];
    const float* eps    = (const float*)d_in[3];
    const float* W1_0   = (const float*)d_in[4];
    const float* b1_0   = (const float*)d_in[5];
    const float* g_0    = (const float*)d_in[6];
    const float* be_0   = (const float*)d_in[7];
    const float* W2_0   = (const float*)d_in[8];
    const float* b2_0   = (const float*)d_in[9];
    const float* W1_r   = (const float*)d_in[10];
    const float* b1_r   = (const float*)d_in[11];
    const float* g_r    = (const float*)d_in[12];
    const float* be_r   = (const float*)d_in[13];
    const float* W2_r   = (const float*)d_in[14];
    const float* b2_r   = (const float*)d_in[15];
    const float* lin1W  = (const float*)d_in[16];
    const float* lin1b  = (const float*)d_in[17];
    const float* bn_g   = (const float*)d_in[18];
    const float* bn_b   = (const float*)d_in[19];
    const float* lin2W  = (const float*)d_in[20];
    const float* lin2b  = (const float*)d_in[21];

    char* ws = (char*)d_ws;
    auto alloc = [&](size_t bytes) {
        char* p = ws;
        ws += (bytes + 255) & ~(size_t)255;
        return p;
    };
    int*      deg     = (int*)alloc((size_t)N_NODES * 4);
    int*      row_ptr = (int*)alloc(((size_t)N_NODES + 1) * 4);
    ushort_t* rank    = (ushort_t*)alloc((size_t)N_EDGES * 2);
    int*      bsum    = (int*)alloc((size_t)N_TILES * 4);
    int*      boff    = (int*)alloc(((size_t)N_TILES + 1) * 4);
    int*      col_src = (int*)alloc((size_t)N_EDGES * 4);
    ushort_t* ybf     = (ushort_t*)alloc((size_t)N_NODES * 64 * 2);
    ushort_t* ubf     = (ushort_t*)alloc((size_t)N_NODES * 64 * 2);
    float*    statsA  = (float*)alloc(NLAYERS * 128 * 4);
    float*    pooled  = (float*)alloc((size_t)N_GRAPHS * 256 * 4);
    float*    t1      = (float*)alloc((size_t)N_GRAPHS * 64 * 4);

    const int e4_grid = (N_EDGES + 1023) / 1024;
    k_zero<<<(N_GRAPHS * 256 + 255) / 256, 256, 0, stream>>>(deg, statsA, pooled);
    k_degree_rank<<<e4_grid, 256, 0, stream>>>(dstArr, deg, rank);
    k_tilesum<<<N_TILES, 256, 0, stream>>>(deg, bsum);
    k_tilescan<<<1, 512, 0, stream>>>(bsum, boff);
    k_tileapply<<<N_TILES, 256, 0, stream>>>(deg, boff, row_ptr);
    k_fill<<<e4_grid, 256, 0, stream>>>(srcArr, dstArr, rank, row_ptr, col_src);

    const int agg_grid  = N_NODES / 4;              // 25000, exact
    const int gemm_grid = (N_NODES + 63) / 64;      // 1563

    // layer 0 front GEMM: y0 = bf16(x @ W1_0)
    k_gemm1<128><<<gemm_grid, 256, 0, stream>>>(x, W1_0, ybf);

    for (int l = 0; l < NLAYERS; ++l) {
        const float *b1, *gg, *be, *W2, *b2;
        if (l == 0) { b1 = b1_0; gg = g_0; be = be_0; W2 = W2_0; b2 = b2_0; }
        else {
            b1 = b1_r + (size_t)(l - 1) * 64;
            gg = g_r  + (size_t)(l - 1) * 64;
            be = be_r + (size_t)(l - 1) * 64;
            W2 = W2_r + (size_t)(l - 1) * 64 * 64;
            b2 = b2_r + (size_t)(l - 1) * 64;
        }
        k_aggregate_u<<<agg_grid, 256, 0, stream>>>((const uint2*)ybf, row_ptr, col_src, eps, l, b1,
                                                    (uint2*)ubf);
        k_stats<<<512, 256, 0, stream>>>((const uint2*)ubf, statsA + l * 128);
        if (l < NLAYERS - 1) {
            const float* W1n = W1_r + (size_t)l * 64 * 64;
            k_fused<true><<<gemm_grid, 256, 0, stream>>>((const uint2*)ubf, W2, statsA + l * 128, gg, be, b2,
                                                         batch, pooled, l, W1n, ybf);
        } else {
            k_fused<false><<<gemm_grid, 256, 0, stream>>>((const uint2*)ubf, W2, statsA + l * 128, gg, be, b2,
                                                          batch, pooled, l, nullptr, nullptr);
        }
    }

    k_head1<<<N_GRAPHS, 64, 0, stream>>>(pooled, lin1W, lin1b, t1);
    k_head3<<<N_GRAPHS, 64, 0, stream>>>(t1, bn_g, bn_b, lin2W, lin2b, (float*)d_out);
}